// Round 2
// baseline (27446.042 us; speedup 1.0000x reference)
//
#include <hip/hip_runtime.h>
#include <hip/hip_bf16.h>

// Decoder_4217657885137: 2-layer LSTM + per-unit random skip-mix, T=512, B=64, H=1024.
//   1) prep_kernel: fp32->bf16 weight conversion (+Wh2 transpose), bias fusion, h-history init, barrier zeroing
//   2) xproj_kernel: Xp[t,b,:] = targets @ W_ih0^T + b_ih0 + b_hh0   (batched over all T; bf16 MFMA)
//   3) seq_kernel (persistent, 192 WGs, PLAIN launch):
//      513 phases; phase p computes layer0(step p) and layer1(step p-1); one grid barrier per phase.
//      R2: coherence moved from the barrier to the DATA (sc0/sc1 H access, relaxed barrier).
//      R3 CHANGE: volatile H LOADS serialized (LLVM orders volatile ops pairwise with waitcnt ->
//        VGPR dropped to 56, one full MALL latency per load, ~36us/phase = measured 42.5us).
//        Replace with relaxed agent-scope atomic loads (same global_load sc0 sc1 encoding, NO
//        forced waitcnt) + manual rolling register prefetch (depth 16 for L0's 2 streams,
//        depth 12 for L1's 3 streams, fully unrolled -> static indices -> registers, no scratch).
//        MALL latency is now paid ~once per phase instead of per-load.
//        H STORES stay volatile (4x 2B per lane; 2B atomic stores risk CAS word-tearing).
//   4) outproj_kernel: y = H1 @ W_out^T + b_out (batched)

#define HID   1024
#define BATCH 64
#define TSEQ  512
#define G4    4096
#define IN0   1536
#define NOUT  512
#define NWG   192
#define NWG_L0 64

typedef __attribute__((ext_vector_type(8))) short bf16x8;
typedef __attribute__((ext_vector_type(4))) float f32x4;
typedef __attribute__((ext_vector_type(2))) unsigned long long u64x2;

#define MFMA16(a,b,c) __builtin_amdgcn_mfma_f32_16x16x32_bf16((a),(b),(c),0,0,0)

__device__ __forceinline__ float bf2f(unsigned short u) {
    return __uint_as_float(((unsigned)u) << 16);
}
__device__ __forceinline__ unsigned short f2bf(float f) {
    unsigned u = __float_as_uint(f);
    u += 0x7fffu + ((u >> 16) & 1u);   // RNE
    return (unsigned short)(u >> 16);
}
__device__ __forceinline__ float sigm(float x)   { return 1.0f / (1.0f + __expf(-x)); }
__device__ __forceinline__ float tanh_f(float x) { return 1.0f - 2.0f / (1.0f + __expf(2.0f * x)); }

// Coherent (cross-XCD) H load: relaxed agent-scope atomic -> global_load_dwordx2 sc0 sc1,
// NO ordering waitcnts (unlike volatile). 16B fragment = two 8B atomic loads.
__device__ __forceinline__ bf16x8 ldcoh(const unsigned short* p) {
    u64x2 u;
    u.x = __hip_atomic_load((const unsigned long long*)p,       __ATOMIC_RELAXED, __HIP_MEMORY_SCOPE_AGENT);
    u.y = __hip_atomic_load((const unsigned long long*)(p + 4), __ATOMIC_RELAXED, __HIP_MEMORY_SCOPE_AGENT);
    return __builtin_bit_cast(bf16x8, u);
}
// Coherent H store: volatile 2B -> global_store_short sc0 sc1 (single instruction, no tearing).
__device__ __forceinline__ void stvol(unsigned short* p, unsigned short v) {
    *(volatile unsigned short*)p = v;
}

// ---------------- prep ----------------
__global__ void prep_kernel(const float* W_ih0, const float* W_hh0, const float* W_ih1, const float* W_hh1,
                            const float* Wh2_0, const float* Wh2_1, const float* W_out,
                            const float* b_ih1, const float* b_hh1, const float* h0_in,
                            unsigned short* Wih0b, unsigned short* Whh0b, unsigned short* Wih1b,
                            unsigned short* Whh1b, unsigned short* Wh2T0b, unsigned short* Wh2T1b,
                            unsigned short* Woutb, float* bias1, unsigned short* H0, unsigned short* H1, int* bar)
{
    const size_t NW0 = (size_t)G4 * IN0;      // 6291456
    const size_t NW  = (size_t)G4 * HID;      // 4194304
    const size_t NT  = (size_t)HID * HID;     // 1048576
    const size_t NO  = (size_t)NOUT * HID;    // 524288
    const size_t NB  = 4096;
    const size_t NH2 = 2 * (size_t)BATCH * HID; // slot0 zeros + slot1 init
    const size_t total = NW0 + 3 * NW + 2 * NT + NO + NB + 2 * NH2 + 512;
    for (size_t i = (size_t)blockIdx.x * blockDim.x + threadIdx.x; i < total;
         i += (size_t)gridDim.x * blockDim.x) {
        size_t x = i;
        if (x < NW0) { Wih0b[x] = f2bf(W_ih0[x]); continue; } x -= NW0;
        if (x < NW)  { Whh0b[x] = f2bf(W_hh0[x]); continue; } x -= NW;
        if (x < NW)  { Wih1b[x] = f2bf(W_ih1[x]); continue; } x -= NW;
        if (x < NW)  { Whh1b[x] = f2bf(W_hh1[x]); continue; } x -= NW;
        if (x < NT)  { size_t j = x >> 10, k = x & 1023; Wh2T0b[x] = f2bf(Wh2_0[k * HID + j]); continue; } x -= NT;
        if (x < NT)  { size_t j = x >> 10, k = x & 1023; Wh2T1b[x] = f2bf(Wh2_1[k * HID + j]); continue; } x -= NT;
        if (x < NO)  { Woutb[x] = f2bf(W_out[x]); continue; } x -= NO;
        if (x < NB)  { bias1[x] = b_ih1[x] + b_hh1[x]; continue; } x -= NB;
        if (x < NH2) { H0[x] = (x < (size_t)BATCH * HID) ? (unsigned short)0
                                                         : f2bf(h0_in[x - (size_t)BATCH * HID]); continue; } x -= NH2;
        if (x < NH2) { H1[x] = (x < (size_t)BATCH * HID) ? (unsigned short)0
                                                         : f2bf(h0_in[(size_t)BATCH * HID + (x - (size_t)BATCH * HID)]); continue; } x -= NH2;
        bar[x] = 0;
    }
}

// ---------------- xproj: Xp = targets @ W_ih0^T + b_ih0 + b_hh0 ----------------
__global__ void __launch_bounds__(256) xproj_kernel(const float* __restrict__ A,
        const unsigned short* __restrict__ Bw, unsigned short* __restrict__ C,
        const float* __restrict__ bi, const float* __restrict__ bh)
{
    const int lane = threadIdx.x & 63, wave = threadIdx.x >> 6;
    const int q = lane >> 4, c = lane & 15;
    const int m0 = blockIdx.y * 64 + wave * 16;
    const int n0 = blockIdx.x * 64;
    const float* arow = A + (size_t)(m0 + c) * IN0 + 8 * q;
    const unsigned short* b0p = Bw + (size_t)(n0 + c) * IN0 + 8 * q;
    const unsigned short* b1p = b0p + (size_t)16 * IN0;
    const unsigned short* b2p = b0p + (size_t)32 * IN0;
    const unsigned short* b3p = b0p + (size_t)48 * IN0;
    f32x4 a0 = {}, a1 = {}, a2 = {}, a3 = {};
    for (int k = 0; k < IN0; k += 32) {
        float4 f0 = *(const float4*)(arow + k);
        float4 f1 = *(const float4*)(arow + k + 4);
        bf16x8 af;
        af[0] = (short)f2bf(f0.x); af[1] = (short)f2bf(f0.y);
        af[2] = (short)f2bf(f0.z); af[3] = (short)f2bf(f0.w);
        af[4] = (short)f2bf(f1.x); af[5] = (short)f2bf(f1.y);
        af[6] = (short)f2bf(f1.z); af[7] = (short)f2bf(f1.w);
        bf16x8 b0 = *(const bf16x8*)(b0p + k);
        bf16x8 b1 = *(const bf16x8*)(b1p + k);
        bf16x8 b2 = *(const bf16x8*)(b2p + k);
        bf16x8 b3 = *(const bf16x8*)(b3p + k);
        a0 = MFMA16(af, b0, a0);
        a1 = MFMA16(af, b1, a1);
        a2 = MFMA16(af, b2, a2);
        a3 = MFMA16(af, b3, a3);
    }
#pragma unroll
    for (int r = 0; r < 4; ++r) {
        const int m = m0 + q * 4 + r;
        unsigned short* crow = C + (size_t)m * G4 + n0 + c;
        crow[0]  = f2bf(a0[r] + bi[n0 + c]      + bh[n0 + c]);
        crow[16] = f2bf(a1[r] + bi[n0 + 16 + c] + bh[n0 + 16 + c]);
        crow[32] = f2bf(a2[r] + bi[n0 + 32 + c] + bh[n0 + 32 + c]);
        crow[48] = f2bf(a3[r] + bi[n0 + 48 + c] + bh[n0 + 48 + c]);
    }
}

// ---------------- outproj: y = H1 @ W_out^T + b_out ----------------
__global__ void __launch_bounds__(256) outproj_kernel(const unsigned short* __restrict__ A,
        const unsigned short* __restrict__ Bw, float* __restrict__ C, const float* __restrict__ bo)
{
    const int lane = threadIdx.x & 63, wave = threadIdx.x >> 6;
    const int q = lane >> 4, c = lane & 15;
    const int m0 = blockIdx.y * 64 + wave * 16;
    const int n0 = blockIdx.x * 64;
    const unsigned short* arow = A + (size_t)(m0 + c) * HID + 8 * q;
    const unsigned short* b0p = Bw + (size_t)(n0 + c) * HID + 8 * q;
    const unsigned short* b1p = b0p + (size_t)16 * HID;
    const unsigned short* b2p = b0p + (size_t)32 * HID;
    const unsigned short* b3p = b0p + (size_t)48 * HID;
    f32x4 a0 = {}, a1 = {}, a2 = {}, a3 = {};
    for (int k = 0; k < HID; k += 32) {
        bf16x8 af = *(const bf16x8*)(arow + k);
        bf16x8 b0 = *(const bf16x8*)(b0p + k);
        bf16x8 b1 = *(const bf16x8*)(b1p + k);
        bf16x8 b2 = *(const bf16x8*)(b2p + k);
        bf16x8 b3 = *(const bf16x8*)(b3p + k);
        a0 = MFMA16(af, b0, a0);
        a1 = MFMA16(af, b1, a1);
        a2 = MFMA16(af, b2, a2);
        a3 = MFMA16(af, b3, a3);
    }
#pragma unroll
    for (int r = 0; r < 4; ++r) {
        const int m = m0 + q * 4 + r;
        float* crow = C + (size_t)m * NOUT + n0 + c;
        crow[0]  = a0[r] + bo[n0 + c];
        crow[16] = a1[r] + bo[n0 + 16 + c];
        crow[32] = a2[r] + bo[n0 + 32 + c];
        crow[48] = a3[r] + bo[n0 + 48 + c];
    }
}

// ---------------- grid barrier (two-level, all-RELAXED agent atomics, NO cache maintenance) ------
// Leaf counters bar[grp*32] (grp=0..7, one 128B line each, 24 WGs per leaf), root bar[256],
// generation bar[288]. H data is sc0/sc1 coherent (MALL-homed), so no buffer_wbl2/buffer_inv:
//  - __syncthreads() drains vmcnt(0) -> every thread's sc1 H-stores are complete at the MALL
//    before thread0 issues its leaf atomic.
//  - reading a fetch_add result forces vmcnt(0) (in-order retirement) -> the leaf/root reset
//    stores are globally visible before the next-level atomic / gen flip is issued.
__device__ __forceinline__ void grid_barrier(int* bar) {
    __syncthreads();
    if (threadIdx.x == 0) {
        const int grp = blockIdx.x & 7;
        int gen = __hip_atomic_load(bar + 288, __ATOMIC_RELAXED, __HIP_MEMORY_SCOPE_AGENT);
        if (__hip_atomic_fetch_add(bar + grp * 32, 1, __ATOMIC_RELAXED, __HIP_MEMORY_SCOPE_AGENT)
            == (NWG / 8 - 1)) {
            __hip_atomic_store(bar + grp * 32, 0, __ATOMIC_RELAXED, __HIP_MEMORY_SCOPE_AGENT);
            if (__hip_atomic_fetch_add(bar + 256, 1, __ATOMIC_RELAXED, __HIP_MEMORY_SCOPE_AGENT) == 7) {
                __hip_atomic_store(bar + 256, 0, __ATOMIC_RELAXED, __HIP_MEMORY_SCOPE_AGENT);
                __hip_atomic_store(bar + 288, gen + 1, __ATOMIC_RELAXED, __HIP_MEMORY_SCOPE_AGENT);
            }
        }
        while (__hip_atomic_load(bar + 288, __ATOMIC_RELAXED, __HIP_MEMORY_SCOPE_AGENT) == gen) {
            __builtin_amdgcn_s_sleep(2);
        }
    }
    __syncthreads();
}

// ---------------- sequential persistent kernel ----------------
// WGs 0..63: layer0, 16 units each. WGs 64..191: layer1 (one step behind), 8 units each.
// H0/H1 slot s = step (s-2) output; slot0 = zeros, slot1 = initial h.
__global__ void __launch_bounds__(256, 1) seq_kernel(
    unsigned short* __restrict__ H0, unsigned short* __restrict__ H1,
    const unsigned short* __restrict__ Xp,
    const unsigned short* __restrict__ Whh0, const unsigned short* __restrict__ Wih1,
    const unsigned short* __restrict__ Whh1,
    const unsigned short* __restrict__ Wh2T0, const unsigned short* __restrict__ Wh2T1,
    const float* __restrict__ bias1, int* bar,
    const float* __restrict__ c0_in, const int* __restrict__ mask,
    const float* __restrict__ bh2_0, const float* __restrict__ bh2_1)
{
    const int wg = blockIdx.x;
    const int lane = threadIdx.x & 63;
    const int wave = threadIdx.x >> 6;
    const int q = lane >> 4, c = lane & 15;
    const int m0 = wave * 16;
    const size_t BH = (size_t)BATCH * HID;

    if (wg < NWG_L0) {
        // ---- layer 0, units j0..j0+15; gates via W_hh0 (A = h0 prev), skip via Wh2T0 (A = h0 skip)
        const int j0 = wg * 16;
        const int j = j0 + c;
        f32x4 creg;
#pragma unroll
        for (int r = 0; r < 4; ++r) creg[r] = c0_in[(size_t)(m0 + q * 4 + r) * HID + j];
        const unsigned short* b0p = Whh0 + (size_t)j * HID + 8 * q;            // ig row j
        const unsigned short* b1p = b0p + (size_t)1024 * HID;                  // fg
        const unsigned short* b2p = b0p + (size_t)2048 * HID;                  // gg
        const unsigned short* b3p = b0p + (size_t)3072 * HID;                  // og
        const unsigned short* bsp = Wh2T0 + (size_t)j * HID + 8 * q;
        const float bsk = bh2_0[j];

        for (int p = 0; p <= TSEQ; ++p) {
            if (p < TSEQ) {
                const unsigned short* arow = H0 + (size_t)(p + 1) * BH + (size_t)(m0 + c) * HID + 8 * q;
                const unsigned short* srow = H0 + (size_t)p * BH + (size_t)(m0 + c) * HID + 8 * q;
                // rolling register prefetch, depth 16 (2 streams x 16 x 16B = 128 VGPR)
                bf16x8 ha[16], hs[16];
#pragma unroll
                for (int kk = 0; kk < 16; ++kk) {
                    ha[kk] = ldcoh(arow + kk * 32);
                    hs[kk] = ldcoh(srow + kk * 32);
                }
                f32x4 a0 = {}, a1 = {}, a2 = {}, a3 = {}, as = {};
#pragma unroll
                for (int it = 0; it < 32; ++it) {
                    bf16x8 af = ha[it & 15];
                    bf16x8 sf = hs[it & 15];
                    if (it + 16 < 32) {
                        ha[it & 15] = ldcoh(arow + (it + 16) * 32);
                        hs[it & 15] = ldcoh(srow + (it + 16) * 32);
                    }
                    const int k = it * 32;
                    bf16x8 b0 = *(const bf16x8*)(b0p + k);
                    bf16x8 b1 = *(const bf16x8*)(b1p + k);
                    bf16x8 b2 = *(const bf16x8*)(b2p + k);
                    bf16x8 b3 = *(const bf16x8*)(b3p + k);
                    a0 = MFMA16(af, b0, a0);
                    a1 = MFMA16(af, b1, a1);
                    a2 = MFMA16(af, b2, a2);
                    a3 = MFMA16(af, b3, a3);
                    bf16x8 bs = *(const bf16x8*)(bsp + k);
                    as = MFMA16(sf, bs, as);
                }
                const int code = mask[(size_t)p * 2048 + j];
                const float m1 = (code == 0 || code == 2) ? 1.f : 0.f;
                const float m2 = (code == 1 || code == 2) ? 1.f : 0.f;
                unsigned short* hout = H0 + (size_t)(p + 2) * BH;
                const unsigned short* xpt = Xp + (size_t)p * BATCH * G4;
#pragma unroll
                for (int r = 0; r < 4; ++r) {
                    const int m = m0 + q * 4 + r;
                    const unsigned short* xr = xpt + (size_t)m * G4 + j;
                    float ig = a0[r] + bf2f(xr[0]);
                    float fg = a1[r] + bf2f(xr[1024]);
                    float gg = a2[r] + bf2f(xr[2048]);
                    float og = a3[r] + bf2f(xr[3072]);
                    float cn = sigm(fg) * creg[r] + sigm(ig) * tanh_f(gg);
                    float h1v = sigm(og) * tanh_f(cn);
                    float h2v = sigm(as[r] + bsk);
                    creg[r] = cn;
                    stvol(hout + (size_t)m * HID + j, f2bf(h1v * m1 + h2v * m2));
                }
            }
            grid_barrier(bar);
        }
    } else {
        // ---- layer 1 (step p-1), units j0..j0+7. N-tiles pack two gates: [ig|fg] and [gg|og].
        const int w1 = wg - NWG_L0;
        const int j0 = w1 * 8;
        const int cj = c & 7, chi = c >> 3;
        const int j = j0 + cj;
        f32x4 creg;
#pragma unroll
        for (int r = 0; r < 4; ++r) creg[r] = c0_in[BH + (size_t)(m0 + q * 4 + r) * HID + j];
        const size_t rowA = (size_t)(j + 1024 * chi) * HID;        // ig (chi=0) | fg (chi=1)
        const size_t rowB = (size_t)(j + 1024 * (2 + chi)) * HID;  // gg | og
        const unsigned short* bi0 = Wih1 + rowA + 8 * q;
        const unsigned short* bi1 = Wih1 + rowB + 8 * q;
        const unsigned short* bh0 = Whh1 + rowA + 8 * q;
        const unsigned short* bh1 = Whh1 + rowB + 8 * q;
        const unsigned short* bsp = Wh2T1 + (size_t)j * HID + 8 * q;
        const float bsk = bh2_1[j];
        const float bg0 = bias1[j], bg1 = bias1[j + 1024], bg2 = bias1[j + 2048], bg3 = bias1[j + 3072];

        for (int p = 0; p <= TSEQ; ++p) {
            if (p >= 1) {
                const int t = p - 1;
                const unsigned short* aih = H0 + (size_t)(p + 1) * BH + (size_t)(m0 + c) * HID + 8 * q;
                const unsigned short* ahh = H1 + (size_t)p * BH + (size_t)(m0 + c) * HID + 8 * q;
                const unsigned short* ask = H1 + (size_t)(p - 1) * BH + (size_t)(m0 + c) * HID + 8 * q;
                // rolling register prefetch, depth 12 (3 streams x 12 x 16B = 144 VGPR)
                bf16x8 hi_[12], hh_[12], hk_[12];
#pragma unroll
                for (int kk = 0; kk < 12; ++kk) {
                    hi_[kk] = ldcoh(aih + kk * 32);
                    hh_[kk] = ldcoh(ahh + kk * 32);
                    hk_[kk] = ldcoh(ask + kk * 32);
                }
                f32x4 x0 = {}, x1 = {}, y0 = {}, y1 = {}, as = {};
#pragma unroll
                for (int it = 0; it < 32; ++it) {
                    bf16x8 fi = hi_[it % 12];
                    bf16x8 fh = hh_[it % 12];
                    bf16x8 fs = hk_[it % 12];
                    if (it + 12 < 32) {
                        hi_[it % 12] = ldcoh(aih + (it + 12) * 32);
                        hh_[it % 12] = ldcoh(ahh + (it + 12) * 32);
                        hk_[it % 12] = ldcoh(ask + (it + 12) * 32);
                    }
                    const int k = it * 32;
                    bf16x8 w0 = *(const bf16x8*)(bi0 + k);
                    bf16x8 w1v = *(const bf16x8*)(bi1 + k);
                    x0 = MFMA16(fi, w0, x0);
                    x1 = MFMA16(fi, w1v, x1);
                    bf16x8 u0 = *(const bf16x8*)(bh0 + k);
                    bf16x8 u1 = *(const bf16x8*)(bh1 + k);
                    y0 = MFMA16(fh, u0, y0);
                    y1 = MFMA16(fh, u1, y1);
                    bf16x8 ws_ = *(const bf16x8*)(bsp + k);
                    as = MFMA16(fs, ws_, as);
                }
                const int code = mask[(size_t)t * 2048 + 1024 + j];
                const float m1 = (code == 0 || code == 2) ? 1.f : 0.f;
                const float m2 = (code == 1 || code == 2) ? 1.f : 0.f;
                unsigned short* hout = H1 + (size_t)(p + 1) * BH;
#pragma unroll
                for (int r = 0; r < 4; ++r) {
                    float t0 = x0[r] + y0[r];               // chi=0: ig[j], chi=1: fg[j]
                    float t1 = x1[r] + y1[r];               // chi=0: gg[j], chi=1: og[j]
                    float pt0 = __shfl_xor(t0, 8, 64);
                    float pt1 = __shfl_xor(t1, 8, 64);
                    if (chi == 0) {
                        float ig = t0 + bg0, fg = pt0 + bg1, gg = t1 + bg2, og = pt1 + bg3;
                        float cn = sigm(fg) * creg[r] + sigm(ig) * tanh_f(gg);
                        float h1v = sigm(og) * tanh_f(cn);
                        float h2v = sigm(as[r] + bsk);
                        creg[r] = cn;
                        const int m = m0 + q * 4 + r;
                        stvol(hout + (size_t)m * HID + j, f2bf(h1v * m1 + h2v * m2));
                    }
                }
            }
            grid_barrier(bar);
        }
    }
}

// ---------------- host ----------------
extern "C" void kernel_launch(void* const* d_in, const int* in_sizes, int n_in,
                              void* d_out, int out_size, void* d_ws, size_t ws_size,
                              hipStream_t stream) {
    const float* targets = (const float*)d_in[0];
    const float* h0_in   = (const float*)d_in[1];
    const float* c0_in   = (const float*)d_in[2];
    const int*   mask    = (const int*)d_in[3];
    const float* W_ih0 = (const float*)d_in[4];
    const float* W_hh0 = (const float*)d_in[5];
    const float* b_ih0 = (const float*)d_in[6];
    const float* b_hh0 = (const float*)d_in[7];
    const float* W_ih1 = (const float*)d_in[8];
    const float* W_hh1 = (const float*)d_in[9];
    const float* b_ih1 = (const float*)d_in[10];
    const float* b_hh1 = (const float*)d_in[11];
    const float* Wh2_0 = (const float*)d_in[12];
    const float* bh2_0 = (const float*)d_in[13];
    const float* Wh2_1 = (const float*)d_in[14];
    const float* bh2_1 = (const float*)d_in[15];
    const float* W_out = (const float*)d_in[16];
    const float* b_out = (const float*)d_in[17];

    char* ws = (char*)d_ws;
    size_t off = 0;
    auto take = [&](size_t bytes) { size_t o = off; off += (bytes + 255) & ~(size_t)255; return o; };
    unsigned short* Xp    = (unsigned short*)(ws + take((size_t)TSEQ * BATCH * G4 * 2));
    unsigned short* H0    = (unsigned short*)(ws + take((size_t)(TSEQ + 2) * BATCH * HID * 2));
    unsigned short* H1    = (unsigned short*)(ws + take((size_t)(TSEQ + 2) * BATCH * HID * 2));
    unsigned short* Wih0b = (unsigned short*)(ws + take((size_t)G4 * IN0 * 2));
    unsigned short* Whh0b = (unsigned short*)(ws + take((size_t)G4 * HID * 2));
    unsigned short* Wih1b = (unsigned short*)(ws + take((size_t)G4 * HID * 2));
    unsigned short* Whh1b = (unsigned short*)(ws + take((size_t)G4 * HID * 2));
    unsigned short* Wh2T0b = (unsigned short*)(ws + take((size_t)HID * HID * 2));
    unsigned short* Wh2T1b = (unsigned short*)(ws + take((size_t)HID * HID * 2));
    unsigned short* Woutb  = (unsigned short*)(ws + take((size_t)NOUT * HID * 2));
    float* bias1 = (float*)(ws + take(4096 * 4));
    int*   bar   = (int*)(ws + take(2048));

    prep_kernel<<<2048, 256, 0, stream>>>(W_ih0, W_hh0, W_ih1, W_hh1, Wh2_0, Wh2_1, W_out,
                                          b_ih1, b_hh1, h0_in,
                                          Wih0b, Whh0b, Wih1b, Whh1b, Wh2T0b, Wh2T1b, Woutb,
                                          bias1, H0, H1, bar);

    xproj_kernel<<<dim3(G4 / 64, TSEQ * BATCH / 64), 256, 0, stream>>>(targets, Wih0b, Xp, b_ih0, b_hh0);

    // PLAIN launch: barrier is hand-rolled (no coop-groups API); 192 blocks @ launch_bounds(256,1)
    // on an idle 256-CU device are all co-resident.
    seq_kernel<<<dim3(NWG), dim3(256), 0, stream>>>(H0, H1, Xp, Whh0b, Wih1b, Whh1b,
                                                    Wh2T0b, Wh2T1b, bias1, bar,
                                                    c0_in, mask, bh2_0, bh2_1);

    outproj_kernel<<<dim3(NOUT / 64, TSEQ * BATCH / 64), 256, 0, stream>>>(
        H1 + 2 * (size_t)BATCH * HID, Woutb, (float*)d_out, b_out);
}

// Round 3
// 26324.799 us; speedup vs baseline: 1.0426x; 1.0426x over previous
//
#include <hip/hip_runtime.h>
#include <hip/hip_bf16.h>

// Decoder_4217657885137: 2-layer LSTM + per-unit random skip-mix, T=512, B=64, H=1024.
//   1) prep_kernel: fp32->bf16 weight conversion (+Wh2 transpose), bias fusion, h-history init, barrier zeroing
//   2) xproj_kernel: Xp[t,b,:] = targets @ W_ih0^T + b_ih0 + b_hh0   (batched over all T; bf16 MFMA)
//   3) seq_kernel (persistent, 192 WGs, PLAIN launch):
//      513 phases; phase p computes layer0(step p) and layer1(step p-1); one grid barrier per phase.
//      R2: relaxed MALL-homed barrier (no buffer_wbl2/buffer_inv -> weights stay L2-resident).
//      R3: atomic-load + register prefetch -> NO change vs R2 => bottleneck is NOT wave-level MLP;
//          sc0/sc1 loads bypass L1+L2, so every WG pulled 256-384KB/phase from MALL (64MB/phase
//          chip-wide, 24x per-XCD redundancy) at a ~50-line/CU concurrency limit = ~44us/phase.
//      R4 CHANGE: H LOADS GO BACK TO PLAIN CACHED LOADS. Safe because slots are write-once at
//        unique addresses within a run: producers store write-through (sc0 sc1 -> MALL updated,
//        no dirty line anywhere), no XCD reads a slot address before the barrier that orders it
//        after the write (so no stale L2 copy can exist), and cross-run/poison staleness is
//        cleared by the dispatch-start acquire (standard HIP inter-kernel coherence). First WG
//        on an XCD faults the slot into its L2; the other WGs (and all skip-stream reads, which
//        touched the same slots last phase) hit L2. H fabric traffic 64MB -> ~2MB/phase.
//   4) outproj_kernel: y = H1 @ W_out^T + b_out (batched)

#define HID   1024
#define BATCH 64
#define TSEQ  512
#define G4    4096
#define IN0   1536
#define NOUT  512
#define NWG   192
#define NWG_L0 64

typedef __attribute__((ext_vector_type(8))) short bf16x8;
typedef __attribute__((ext_vector_type(4))) float f32x4;

#define MFMA16(a,b,c) __builtin_amdgcn_mfma_f32_16x16x32_bf16((a),(b),(c),0,0,0)

__device__ __forceinline__ float bf2f(unsigned short u) {
    return __uint_as_float(((unsigned)u) << 16);
}
__device__ __forceinline__ unsigned short f2bf(float f) {
    unsigned u = __float_as_uint(f);
    u += 0x7fffu + ((u >> 16) & 1u);   // RNE
    return (unsigned short)(u >> 16);
}
__device__ __forceinline__ float sigm(float x)   { return 1.0f / (1.0f + __expf(-x)); }
__device__ __forceinline__ float tanh_f(float x) { return 1.0f - 2.0f / (1.0f + __expf(2.0f * x)); }

// Coherent H store: volatile 2B -> global_store_short sc0 sc1 (write-through to MALL, the
// cross-XCD coherence point; single instruction, no tearing).
__device__ __forceinline__ void stvol(unsigned short* p, unsigned short v) {
    *(volatile unsigned short*)p = v;
}

// ---------------- prep ----------------
__global__ void prep_kernel(const float* W_ih0, const float* W_hh0, const float* W_ih1, const float* W_hh1,
                            const float* Wh2_0, const float* Wh2_1, const float* W_out,
                            const float* b_ih1, const float* b_hh1, const float* h0_in,
                            unsigned short* Wih0b, unsigned short* Whh0b, unsigned short* Wih1b,
                            unsigned short* Whh1b, unsigned short* Wh2T0b, unsigned short* Wh2T1b,
                            unsigned short* Woutb, float* bias1, unsigned short* H0, unsigned short* H1, int* bar)
{
    const size_t NW0 = (size_t)G4 * IN0;      // 6291456
    const size_t NW  = (size_t)G4 * HID;      // 4194304
    const size_t NT  = (size_t)HID * HID;     // 1048576
    const size_t NO  = (size_t)NOUT * HID;    // 524288
    const size_t NB  = 4096;
    const size_t NH2 = 2 * (size_t)BATCH * HID; // slot0 zeros + slot1 init
    const size_t total = NW0 + 3 * NW + 2 * NT + NO + NB + 2 * NH2 + 512;
    for (size_t i = (size_t)blockIdx.x * blockDim.x + threadIdx.x; i < total;
         i += (size_t)gridDim.x * blockDim.x) {
        size_t x = i;
        if (x < NW0) { Wih0b[x] = f2bf(W_ih0[x]); continue; } x -= NW0;
        if (x < NW)  { Whh0b[x] = f2bf(W_hh0[x]); continue; } x -= NW;
        if (x < NW)  { Wih1b[x] = f2bf(W_ih1[x]); continue; } x -= NW;
        if (x < NW)  { Whh1b[x] = f2bf(W_hh1[x]); continue; } x -= NW;
        if (x < NT)  { size_t j = x >> 10, k = x & 1023; Wh2T0b[x] = f2bf(Wh2_0[k * HID + j]); continue; } x -= NT;
        if (x < NT)  { size_t j = x >> 10, k = x & 1023; Wh2T1b[x] = f2bf(Wh2_1[k * HID + j]); continue; } x -= NT;
        if (x < NO)  { Woutb[x] = f2bf(W_out[x]); continue; } x -= NO;
        if (x < NB)  { bias1[x] = b_ih1[x] + b_hh1[x]; continue; } x -= NB;
        if (x < NH2) { H0[x] = (x < (size_t)BATCH * HID) ? (unsigned short)0
                                                         : f2bf(h0_in[x - (size_t)BATCH * HID]); continue; } x -= NH2;
        if (x < NH2) { H1[x] = (x < (size_t)BATCH * HID) ? (unsigned short)0
                                                         : f2bf(h0_in[(size_t)BATCH * HID + (x - (size_t)BATCH * HID)]); continue; } x -= NH2;
        bar[x] = 0;
    }
}

// ---------------- xproj: Xp = targets @ W_ih0^T + b_ih0 + b_hh0 ----------------
__global__ void __launch_bounds__(256) xproj_kernel(const float* __restrict__ A,
        const unsigned short* __restrict__ Bw, unsigned short* __restrict__ C,
        const float* __restrict__ bi, const float* __restrict__ bh)
{
    const int lane = threadIdx.x & 63, wave = threadIdx.x >> 6;
    const int q = lane >> 4, c = lane & 15;
    const int m0 = blockIdx.y * 64 + wave * 16;
    const int n0 = blockIdx.x * 64;
    const float* arow = A + (size_t)(m0 + c) * IN0 + 8 * q;
    const unsigned short* b0p = Bw + (size_t)(n0 + c) * IN0 + 8 * q;
    const unsigned short* b1p = b0p + (size_t)16 * IN0;
    const unsigned short* b2p = b0p + (size_t)32 * IN0;
    const unsigned short* b3p = b0p + (size_t)48 * IN0;
    f32x4 a0 = {}, a1 = {}, a2 = {}, a3 = {};
    for (int k = 0; k < IN0; k += 32) {
        float4 f0 = *(const float4*)(arow + k);
        float4 f1 = *(const float4*)(arow + k + 4);
        bf16x8 af;
        af[0] = (short)f2bf(f0.x); af[1] = (short)f2bf(f0.y);
        af[2] = (short)f2bf(f0.z); af[3] = (short)f2bf(f0.w);
        af[4] = (short)f2bf(f1.x); af[5] = (short)f2bf(f1.y);
        af[6] = (short)f2bf(f1.z); af[7] = (short)f2bf(f1.w);
        bf16x8 b0 = *(const bf16x8*)(b0p + k);
        bf16x8 b1 = *(const bf16x8*)(b1p + k);
        bf16x8 b2 = *(const bf16x8*)(b2p + k);
        bf16x8 b3 = *(const bf16x8*)(b3p + k);
        a0 = MFMA16(af, b0, a0);
        a1 = MFMA16(af, b1, a1);
        a2 = MFMA16(af, b2, a2);
        a3 = MFMA16(af, b3, a3);
    }
#pragma unroll
    for (int r = 0; r < 4; ++r) {
        const int m = m0 + q * 4 + r;
        unsigned short* crow = C + (size_t)m * G4 + n0 + c;
        crow[0]  = f2bf(a0[r] + bi[n0 + c]      + bh[n0 + c]);
        crow[16] = f2bf(a1[r] + bi[n0 + 16 + c] + bh[n0 + 16 + c]);
        crow[32] = f2bf(a2[r] + bi[n0 + 32 + c] + bh[n0 + 32 + c]);
        crow[48] = f2bf(a3[r] + bi[n0 + 48 + c] + bh[n0 + 48 + c]);
    }
}

// ---------------- outproj: y = H1 @ W_out^T + b_out ----------------
__global__ void __launch_bounds__(256) outproj_kernel(const unsigned short* __restrict__ A,
        const unsigned short* __restrict__ Bw, float* __restrict__ C, const float* __restrict__ bo)
{
    const int lane = threadIdx.x & 63, wave = threadIdx.x >> 6;
    const int q = lane >> 4, c = lane & 15;
    const int m0 = blockIdx.y * 64 + wave * 16;
    const int n0 = blockIdx.x * 64;
    const unsigned short* arow = A + (size_t)(m0 + c) * HID + 8 * q;
    const unsigned short* b0p = Bw + (size_t)(n0 + c) * HID + 8 * q;
    const unsigned short* b1p = b0p + (size_t)16 * HID;
    const unsigned short* b2p = b0p + (size_t)32 * HID;
    const unsigned short* b3p = b0p + (size_t)48 * HID;
    f32x4 a0 = {}, a1 = {}, a2 = {}, a3 = {};
    for (int k = 0; k < HID; k += 32) {
        bf16x8 af = *(const bf16x8*)(arow + k);
        bf16x8 b0 = *(const bf16x8*)(b0p + k);
        bf16x8 b1 = *(const bf16x8*)(b1p + k);
        bf16x8 b2 = *(const bf16x8*)(b2p + k);
        bf16x8 b3 = *(const bf16x8*)(b3p + k);
        a0 = MFMA16(af, b0, a0);
        a1 = MFMA16(af, b1, a1);
        a2 = MFMA16(af, b2, a2);
        a3 = MFMA16(af, b3, a3);
    }
#pragma unroll
    for (int r = 0; r < 4; ++r) {
        const int m = m0 + q * 4 + r;
        float* crow = C + (size_t)m * NOUT + n0 + c;
        crow[0]  = a0[r] + bo[n0 + c];
        crow[16] = a1[r] + bo[n0 + 16 + c];
        crow[32] = a2[r] + bo[n0 + 32 + c];
        crow[48] = a3[r] + bo[n0 + 48 + c];
    }
}

// ---------------- grid barrier (two-level, all-RELAXED agent atomics, NO cache maintenance) ------
// Leaf counters bar[grp*32] (grp=0..7, one 128B line each, 24 WGs per leaf), root bar[256],
// generation bar[288]. H stores are sc0/sc1 write-through (MALL-homed):
//  - __syncthreads() drains vmcnt(0) -> every thread's sc1 H-stores have reached the MALL
//    before thread0 issues its leaf atomic.
//  - reading a fetch_add result forces vmcnt(0) (in-order retirement) -> the leaf/root reset
//    stores are globally visible before the next-level atomic / gen flip is issued.
__device__ __forceinline__ void grid_barrier(int* bar) {
    __syncthreads();
    if (threadIdx.x == 0) {
        const int grp = blockIdx.x & 7;
        int gen = __hip_atomic_load(bar + 288, __ATOMIC_RELAXED, __HIP_MEMORY_SCOPE_AGENT);
        if (__hip_atomic_fetch_add(bar + grp * 32, 1, __ATOMIC_RELAXED, __HIP_MEMORY_SCOPE_AGENT)
            == (NWG / 8 - 1)) {
            __hip_atomic_store(bar + grp * 32, 0, __ATOMIC_RELAXED, __HIP_MEMORY_SCOPE_AGENT);
            if (__hip_atomic_fetch_add(bar + 256, 1, __ATOMIC_RELAXED, __HIP_MEMORY_SCOPE_AGENT) == 7) {
                __hip_atomic_store(bar + 256, 0, __ATOMIC_RELAXED, __HIP_MEMORY_SCOPE_AGENT);
                __hip_atomic_store(bar + 288, gen + 1, __ATOMIC_RELAXED, __HIP_MEMORY_SCOPE_AGENT);
            }
        }
        while (__hip_atomic_load(bar + 288, __ATOMIC_RELAXED, __HIP_MEMORY_SCOPE_AGENT) == gen) {
            __builtin_amdgcn_s_sleep(2);
        }
    }
    __syncthreads();
}

// ---------------- sequential persistent kernel ----------------
// WGs 0..63: layer0, 16 units each. WGs 64..191: layer1 (one step behind), 8 units each.
// H0/H1 slot s = step (s-2) output; slot0 = zeros, slot1 = initial h.
// H reads are PLAIN cached loads (write-once slots; see header). H writes are sc0/sc1.
__global__ void __launch_bounds__(256, 1) seq_kernel(
    unsigned short* __restrict__ H0, unsigned short* __restrict__ H1,
    const unsigned short* __restrict__ Xp,
    const unsigned short* __restrict__ Whh0, const unsigned short* __restrict__ Wih1,
    const unsigned short* __restrict__ Whh1,
    const unsigned short* __restrict__ Wh2T0, const unsigned short* __restrict__ Wh2T1,
    const float* __restrict__ bias1, int* bar,
    const float* __restrict__ c0_in, const int* __restrict__ mask,
    const float* __restrict__ bh2_0, const float* __restrict__ bh2_1)
{
    const int wg = blockIdx.x;
    const int lane = threadIdx.x & 63;
    const int wave = threadIdx.x >> 6;
    const int q = lane >> 4, c = lane & 15;
    const int m0 = wave * 16;
    const size_t BH = (size_t)BATCH * HID;

    if (wg < NWG_L0) {
        // ---- layer 0, units j0..j0+15; gates via W_hh0 (A = h0 prev), skip via Wh2T0 (A = h0 skip)
        const int j0 = wg * 16;
        const int j = j0 + c;
        f32x4 creg;
#pragma unroll
        for (int r = 0; r < 4; ++r) creg[r] = c0_in[(size_t)(m0 + q * 4 + r) * HID + j];
        const unsigned short* b0p = Whh0 + (size_t)j * HID + 8 * q;            // ig row j
        const unsigned short* b1p = b0p + (size_t)1024 * HID;                  // fg
        const unsigned short* b2p = b0p + (size_t)2048 * HID;                  // gg
        const unsigned short* b3p = b0p + (size_t)3072 * HID;                  // og
        const unsigned short* bsp = Wh2T0 + (size_t)j * HID + 8 * q;
        const float bsk = bh2_0[j];

        for (int p = 0; p <= TSEQ; ++p) {
            if (p < TSEQ) {
                const unsigned short* arow = H0 + (size_t)(p + 1) * BH + (size_t)(m0 + c) * HID + 8 * q;
                const unsigned short* srow = H0 + (size_t)p * BH + (size_t)(m0 + c) * HID + 8 * q;
                f32x4 a0 = {}, a1 = {}, a2 = {}, a3 = {}, as = {};
                for (int k = 0; k < HID; k += 32) {
                    bf16x8 af = *(const bf16x8*)(arow + k);
                    bf16x8 b0 = *(const bf16x8*)(b0p + k);
                    bf16x8 b1 = *(const bf16x8*)(b1p + k);
                    bf16x8 b2 = *(const bf16x8*)(b2p + k);
                    bf16x8 b3 = *(const bf16x8*)(b3p + k);
                    a0 = MFMA16(af, b0, a0);
                    a1 = MFMA16(af, b1, a1);
                    a2 = MFMA16(af, b2, a2);
                    a3 = MFMA16(af, b3, a3);
                    bf16x8 sf = *(const bf16x8*)(srow + k);
                    bf16x8 bs = *(const bf16x8*)(bsp + k);
                    as = MFMA16(sf, bs, as);
                }
                const int code = mask[(size_t)p * 2048 + j];
                const float m1 = (code == 0 || code == 2) ? 1.f : 0.f;
                const float m2 = (code == 1 || code == 2) ? 1.f : 0.f;
                unsigned short* hout = H0 + (size_t)(p + 2) * BH;
                const unsigned short* xpt = Xp + (size_t)p * BATCH * G4;
#pragma unroll
                for (int r = 0; r < 4; ++r) {
                    const int m = m0 + q * 4 + r;
                    const unsigned short* xr = xpt + (size_t)m * G4 + j;
                    float ig = a0[r] + bf2f(xr[0]);
                    float fg = a1[r] + bf2f(xr[1024]);
                    float gg = a2[r] + bf2f(xr[2048]);
                    float og = a3[r] + bf2f(xr[3072]);
                    float cn = sigm(fg) * creg[r] + sigm(ig) * tanh_f(gg);
                    float h1v = sigm(og) * tanh_f(cn);
                    float h2v = sigm(as[r] + bsk);
                    creg[r] = cn;
                    stvol(hout + (size_t)m * HID + j, f2bf(h1v * m1 + h2v * m2));
                }
            }
            grid_barrier(bar);
        }
    } else {
        // ---- layer 1 (step p-1), units j0..j0+7. N-tiles pack two gates: [ig|fg] and [gg|og].
        const int w1 = wg - NWG_L0;
        const int j0 = w1 * 8;
        const int cj = c & 7, chi = c >> 3;
        const int j = j0 + cj;
        f32x4 creg;
#pragma unroll
        for (int r = 0; r < 4; ++r) creg[r] = c0_in[BH + (size_t)(m0 + q * 4 + r) * HID + j];
        const size_t rowA = (size_t)(j + 1024 * chi) * HID;        // ig (chi=0) | fg (chi=1)
        const size_t rowB = (size_t)(j + 1024 * (2 + chi)) * HID;  // gg | og
        const unsigned short* bi0 = Wih1 + rowA + 8 * q;
        const unsigned short* bi1 = Wih1 + rowB + 8 * q;
        const unsigned short* bh0 = Whh1 + rowA + 8 * q;
        const unsigned short* bh1 = Whh1 + rowB + 8 * q;
        const unsigned short* bsp = Wh2T1 + (size_t)j * HID + 8 * q;
        const float bsk = bh2_1[j];
        const float bg0 = bias1[j], bg1 = bias1[j + 1024], bg2 = bias1[j + 2048], bg3 = bias1[j + 3072];

        for (int p = 0; p <= TSEQ; ++p) {
            if (p >= 1) {
                const int t = p - 1;
                const unsigned short* aih = H0 + (size_t)(p + 1) * BH + (size_t)(m0 + c) * HID + 8 * q;
                const unsigned short* ahh = H1 + (size_t)p * BH + (size_t)(m0 + c) * HID + 8 * q;
                const unsigned short* ask = H1 + (size_t)(p - 1) * BH + (size_t)(m0 + c) * HID + 8 * q;
                f32x4 x0 = {}, x1 = {}, y0 = {}, y1 = {}, as = {};
                for (int k = 0; k < HID; k += 32) {
                    bf16x8 fi = *(const bf16x8*)(aih + k);
                    bf16x8 w0 = *(const bf16x8*)(bi0 + k);
                    bf16x8 w1v = *(const bf16x8*)(bi1 + k);
                    x0 = MFMA16(fi, w0, x0);
                    x1 = MFMA16(fi, w1v, x1);
                    bf16x8 fh = *(const bf16x8*)(ahh + k);
                    bf16x8 u0 = *(const bf16x8*)(bh0 + k);
                    bf16x8 u1 = *(const bf16x8*)(bh1 + k);
                    y0 = MFMA16(fh, u0, y0);
                    y1 = MFMA16(fh, u1, y1);
                    bf16x8 fs = *(const bf16x8*)(ask + k);
                    bf16x8 ws_ = *(const bf16x8*)(bsp + k);
                    as = MFMA16(fs, ws_, as);
                }
                const int code = mask[(size_t)t * 2048 + 1024 + j];
                const float m1 = (code == 0 || code == 2) ? 1.f : 0.f;
                const float m2 = (code == 1 || code == 2) ? 1.f : 0.f;
                unsigned short* hout = H1 + (size_t)(p + 1) * BH;
#pragma unroll
                for (int r = 0; r < 4; ++r) {
                    float t0 = x0[r] + y0[r];               // chi=0: ig[j], chi=1: fg[j]
                    float t1 = x1[r] + y1[r];               // chi=0: gg[j], chi=1: og[j]
                    float pt0 = __shfl_xor(t0, 8, 64);
                    float pt1 = __shfl_xor(t1, 8, 64);
                    if (chi == 0) {
                        float ig = t0 + bg0, fg = pt0 + bg1, gg = t1 + bg2, og = pt1 + bg3;
                        float cn = sigm(fg) * creg[r] + sigm(ig) * tanh_f(gg);
                        float h1v = sigm(og) * tanh_f(cn);
                        float h2v = sigm(as[r] + bsk);
                        creg[r] = cn;
                        const int m = m0 + q * 4 + r;
                        stvol(hout + (size_t)m * HID + j, f2bf(h1v * m1 + h2v * m2));
                    }
                }
            }
            grid_barrier(bar);
        }
    }
}

// ---------------- host ----------------
extern "C" void kernel_launch(void* const* d_in, const int* in_sizes, int n_in,
                              void* d_out, int out_size, void* d_ws, size_t ws_size,
                              hipStream_t stream) {
    const float* targets = (const float*)d_in[0];
    const float* h0_in   = (const float*)d_in[1];
    const float* c0_in   = (const float*)d_in[2];
    const int*   mask    = (const int*)d_in[3];
    const float* W_ih0 = (const float*)d_in[4];
    const float* W_hh0 = (const float*)d_in[5];
    const float* b_ih0 = (const float*)d_in[6];
    const float* b_hh0 = (const float*)d_in[7];
    const float* W_ih1 = (const float*)d_in[8];
    const float* W_hh1 = (const float*)d_in[9];
    const float* b_ih1 = (const float*)d_in[10];
    const float* b_hh1 = (const float*)d_in[11];
    const float* Wh2_0 = (const float*)d_in[12];
    const float* bh2_0 = (const float*)d_in[13];
    const float* Wh2_1 = (const float*)d_in[14];
    const float* bh2_1 = (const float*)d_in[15];
    const float* W_out = (const float*)d_in[16];
    const float* b_out = (const float*)d_in[17];

    char* ws = (char*)d_ws;
    size_t off = 0;
    auto take = [&](size_t bytes) { size_t o = off; off += (bytes + 255) & ~(size_t)255; return o; };
    unsigned short* Xp    = (unsigned short*)(ws + take((size_t)TSEQ * BATCH * G4 * 2));
    unsigned short* H0    = (unsigned short*)(ws + take((size_t)(TSEQ + 2) * BATCH * HID * 2));
    unsigned short* H1    = (unsigned short*)(ws + take((size_t)(TSEQ + 2) * BATCH * HID * 2));
    unsigned short* Wih0b = (unsigned short*)(ws + take((size_t)G4 * IN0 * 2));
    unsigned short* Whh0b = (unsigned short*)(ws + take((size_t)G4 * HID * 2));
    unsigned short* Wih1b = (unsigned short*)(ws + take((size_t)G4 * HID * 2));
    unsigned short* Whh1b = (unsigned short*)(ws + take((size_t)G4 * HID * 2));
    unsigned short* Wh2T0b = (unsigned short*)(ws + take((size_t)HID * HID * 2));
    unsigned short* Wh2T1b = (unsigned short*)(ws + take((size_t)HID * HID * 2));
    unsigned short* Woutb  = (unsigned short*)(ws + take((size_t)NOUT * HID * 2));
    float* bias1 = (float*)(ws + take(4096 * 4));
    int*   bar   = (int*)(ws + take(2048));

    prep_kernel<<<2048, 256, 0, stream>>>(W_ih0, W_hh0, W_ih1, W_hh1, Wh2_0, Wh2_1, W_out,
                                          b_ih1, b_hh1, h0_in,
                                          Wih0b, Whh0b, Wih1b, Whh1b, Wh2T0b, Wh2T1b, Woutb,
                                          bias1, H0, H1, bar);

    xproj_kernel<<<dim3(G4 / 64, TSEQ * BATCH / 64), 256, 0, stream>>>(targets, Wih0b, Xp, b_ih0, b_hh0);

    // PLAIN launch: barrier is hand-rolled (no coop-groups API); 192 blocks @ launch_bounds(256,1)
    // on an idle 256-CU device are all co-resident.
    seq_kernel<<<dim3(NWG), dim3(256), 0, stream>>>(H0, H1, Xp, Whh0b, Wih1b, Whh1b,
                                                    Wh2T0b, Wh2T1b, bias1, bar,
                                                    c0_in, mask, bh2_0, bh2_1);

    outproj_kernel<<<dim3(NOUT / 64, TSEQ * BATCH / 64), 256, 0, stream>>>(
        H1 + 2 * (size_t)BATCH * HID, Woutb, (float*)d_out, b_out);
}

// Round 4
// 17926.485 us; speedup vs baseline: 1.5310x; 1.4685x over previous
//
#include <hip/hip_runtime.h>
#include <hip/hip_bf16.h>

// Decoder_4217657885137: 2-layer LSTM + per-unit random skip-mix, T=512, B=64, H=1024.
//   1) prep_kernel: fp32->bf16 weight conversion (+Wh2 transpose), bias fusion, h-history init, barrier zeroing
//   2) xproj_kernel: Xp[t,b,:] = targets @ W_ih0^T + b_ih0 + b_hh0   (batched over all T; bf16 MFMA)
//   3) seq_kernel (persistent, 192 WGs, PLAIN launch):
//      513 phases; phase p computes layer0(step p) and layer1(step p-1); one grid barrier per phase.
//      R2: relaxed MALL-homed barrier. R3: atomic loads+prefetch (no change). R4: plain cached H
//      loads (no change). LESSON: phase time (42us) is INVARIANT to the H-load path. The measured
//      anomaly is FETCH_SIZE = 12 MB/phase of L2-miss traffic vs ~2.5 MB expected: per-XCD weight
//      working set (3.5 MB) + Xp/H streaming vs 4 MB L2 -> weights refetched from HBM every phase.
//      R5 CHANGES:
//        a) 64 KiB static LDS pins HALF of each WG's weights (L0: ig/fg gate rows; L1: all Wih1),
//           XOR-swizzled (byte ^ ((row&7)<<4)) so wave64 ds_read_b128 is at the 8-cycle floor.
//           Residual global weights/XCD ~2 MB < 4 MB L2 -> no more per-phase HBM refetch.
//        b) Xp reads: non-temporal (read-once stream, don't evict weights) + issued BEFORE the
//           k-loop so miss latency hides under MFMA instead of serializing in the epilogue.
//        c) bar_diag_kernel: 256 pure grid-barriers, same 192-WG shape, separate counters, run
//           last -> isolates the barrier's per-phase cost in the dispatch table / total time.
//   4) outproj_kernel: y = H1 @ W_out^T + b_out (batched)

#define HID   1024
#define BATCH 64
#define TSEQ  512
#define G4    4096
#define IN0   1536
#define NOUT  512
#define NWG   192
#define NWG_L0 64

typedef __attribute__((ext_vector_type(8))) short bf16x8;
typedef __attribute__((ext_vector_type(4))) float f32x4;

#define MFMA16(a,b,c) __builtin_amdgcn_mfma_f32_16x16x32_bf16((a),(b),(c),0,0,0)

__device__ __forceinline__ float bf2f(unsigned short u) {
    return __uint_as_float(((unsigned)u) << 16);
}
__device__ __forceinline__ unsigned short f2bf(float f) {
    unsigned u = __float_as_uint(f);
    u += 0x7fffu + ((u >> 16) & 1u);   // RNE
    return (unsigned short)(u >> 16);
}
__device__ __forceinline__ float sigm(float x)   { return 1.0f / (1.0f + __expf(-x)); }
__device__ __forceinline__ float tanh_f(float x) { return 1.0f - 2.0f / (1.0f + __expf(2.0f * x)); }

// Coherent H store: volatile 2B -> global_store_short sc0 sc1 (write-through to MALL, the
// cross-XCD coherence point; single instruction, no tearing).
__device__ __forceinline__ void stvol(unsigned short* p, unsigned short v) {
    *(volatile unsigned short*)p = v;
}

// ---------------- prep ----------------
__global__ void prep_kernel(const float* W_ih0, const float* W_hh0, const float* W_ih1, const float* W_hh1,
                            const float* Wh2_0, const float* Wh2_1, const float* W_out,
                            const float* b_ih1, const float* b_hh1, const float* h0_in,
                            unsigned short* Wih0b, unsigned short* Whh0b, unsigned short* Wih1b,
                            unsigned short* Whh1b, unsigned short* Wh2T0b, unsigned short* Wh2T1b,
                            unsigned short* Woutb, float* bias1, unsigned short* H0, unsigned short* H1, int* bar)
{
    const size_t NW0 = (size_t)G4 * IN0;      // 6291456
    const size_t NW  = (size_t)G4 * HID;      // 4194304
    const size_t NT  = (size_t)HID * HID;     // 1048576
    const size_t NO  = (size_t)NOUT * HID;    // 524288
    const size_t NB  = 4096;
    const size_t NH2 = 2 * (size_t)BATCH * HID; // slot0 zeros + slot1 init
    const size_t total = NW0 + 3 * NW + 2 * NT + NO + NB + 2 * NH2 + 1024;
    for (size_t i = (size_t)blockIdx.x * blockDim.x + threadIdx.x; i < total;
         i += (size_t)gridDim.x * blockDim.x) {
        size_t x = i;
        if (x < NW0) { Wih0b[x] = f2bf(W_ih0[x]); continue; } x -= NW0;
        if (x < NW)  { Whh0b[x] = f2bf(W_hh0[x]); continue; } x -= NW;
        if (x < NW)  { Wih1b[x] = f2bf(W_ih1[x]); continue; } x -= NW;
        if (x < NW)  { Whh1b[x] = f2bf(W_hh1[x]); continue; } x -= NW;
        if (x < NT)  { size_t j = x >> 10, k = x & 1023; Wh2T0b[x] = f2bf(Wh2_0[k * HID + j]); continue; } x -= NT;
        if (x < NT)  { size_t j = x >> 10, k = x & 1023; Wh2T1b[x] = f2bf(Wh2_1[k * HID + j]); continue; } x -= NT;
        if (x < NO)  { Woutb[x] = f2bf(W_out[x]); continue; } x -= NO;
        if (x < NB)  { bias1[x] = b_ih1[x] + b_hh1[x]; continue; } x -= NB;
        if (x < NH2) { H0[x] = (x < (size_t)BATCH * HID) ? (unsigned short)0
                                                         : f2bf(h0_in[x - (size_t)BATCH * HID]); continue; } x -= NH2;
        if (x < NH2) { H1[x] = (x < (size_t)BATCH * HID) ? (unsigned short)0
                                                         : f2bf(h0_in[(size_t)BATCH * HID + (x - (size_t)BATCH * HID)]); continue; } x -= NH2;
        bar[x] = 0;
    }
}

// ---------------- xproj: Xp = targets @ W_ih0^T + b_ih0 + b_hh0 ----------------
__global__ void __launch_bounds__(256) xproj_kernel(const float* __restrict__ A,
        const unsigned short* __restrict__ Bw, unsigned short* __restrict__ C,
        const float* __restrict__ bi, const float* __restrict__ bh)
{
    const int lane = threadIdx.x & 63, wave = threadIdx.x >> 6;
    const int q = lane >> 4, c = lane & 15;
    const int m0 = blockIdx.y * 64 + wave * 16;
    const int n0 = blockIdx.x * 64;
    const float* arow = A + (size_t)(m0 + c) * IN0 + 8 * q;
    const unsigned short* b0p = Bw + (size_t)(n0 + c) * IN0 + 8 * q;
    const unsigned short* b1p = b0p + (size_t)16 * IN0;
    const unsigned short* b2p = b0p + (size_t)32 * IN0;
    const unsigned short* b3p = b0p + (size_t)48 * IN0;
    f32x4 a0 = {}, a1 = {}, a2 = {}, a3 = {};
    for (int k = 0; k < IN0; k += 32) {
        float4 f0 = *(const float4*)(arow + k);
        float4 f1 = *(const float4*)(arow + k + 4);
        bf16x8 af;
        af[0] = (short)f2bf(f0.x); af[1] = (short)f2bf(f0.y);
        af[2] = (short)f2bf(f0.z); af[3] = (short)f2bf(f0.w);
        af[4] = (short)f2bf(f1.x); af[5] = (short)f2bf(f1.y);
        af[6] = (short)f2bf(f1.z); af[7] = (short)f2bf(f1.w);
        bf16x8 b0 = *(const bf16x8*)(b0p + k);
        bf16x8 b1 = *(const bf16x8*)(b1p + k);
        bf16x8 b2 = *(const bf16x8*)(b2p + k);
        bf16x8 b3 = *(const bf16x8*)(b3p + k);
        a0 = MFMA16(af, b0, a0);
        a1 = MFMA16(af, b1, a1);
        a2 = MFMA16(af, b2, a2);
        a3 = MFMA16(af, b3, a3);
    }
#pragma unroll
    for (int r = 0; r < 4; ++r) {
        const int m = m0 + q * 4 + r;
        unsigned short* crow = C + (size_t)m * G4 + n0 + c;
        crow[0]  = f2bf(a0[r] + bi[n0 + c]      + bh[n0 + c]);
        crow[16] = f2bf(a1[r] + bi[n0 + 16 + c] + bh[n0 + 16 + c]);
        crow[32] = f2bf(a2[r] + bi[n0 + 32 + c] + bh[n0 + 32 + c]);
        crow[48] = f2bf(a3[r] + bi[n0 + 48 + c] + bh[n0 + 48 + c]);
    }
}

// ---------------- outproj: y = H1 @ W_out^T + b_out ----------------
__global__ void __launch_bounds__(256) outproj_kernel(const unsigned short* __restrict__ A,
        const unsigned short* __restrict__ Bw, float* __restrict__ C, const float* __restrict__ bo)
{
    const int lane = threadIdx.x & 63, wave = threadIdx.x >> 6;
    const int q = lane >> 4, c = lane & 15;
    const int m0 = blockIdx.y * 64 + wave * 16;
    const int n0 = blockIdx.x * 64;
    const unsigned short* arow = A + (size_t)(m0 + c) * HID + 8 * q;
    const unsigned short* b0p = Bw + (size_t)(n0 + c) * HID + 8 * q;
    const unsigned short* b1p = b0p + (size_t)16 * HID;
    const unsigned short* b2p = b0p + (size_t)32 * HID;
    const unsigned short* b3p = b0p + (size_t)48 * HID;
    f32x4 a0 = {}, a1 = {}, a2 = {}, a3 = {};
    for (int k = 0; k < HID; k += 32) {
        bf16x8 af = *(const bf16x8*)(arow + k);
        bf16x8 b0 = *(const bf16x8*)(b0p + k);
        bf16x8 b1 = *(const bf16x8*)(b1p + k);
        bf16x8 b2 = *(const bf16x8*)(b2p + k);
        bf16x8 b3 = *(const bf16x8*)(b3p + k);
        a0 = MFMA16(af, b0, a0);
        a1 = MFMA16(af, b1, a1);
        a2 = MFMA16(af, b2, a2);
        a3 = MFMA16(af, b3, a3);
    }
#pragma unroll
    for (int r = 0; r < 4; ++r) {
        const int m = m0 + q * 4 + r;
        float* crow = C + (size_t)m * NOUT + n0 + c;
        crow[0]  = a0[r] + bo[n0 + c];
        crow[16] = a1[r] + bo[n0 + 16 + c];
        crow[32] = a2[r] + bo[n0 + 32 + c];
        crow[48] = a3[r] + bo[n0 + 48 + c];
    }
}

// ---------------- grid barrier (two-level, all-RELAXED agent atomics, NO cache maintenance) ------
// Leaf counters bar[grp*32] (grp=0..7, one 128B line each, 24 WGs per leaf), root bar[256],
// generation bar[288]. H stores are sc0/sc1 write-through (MALL-homed):
//  - __syncthreads() drains vmcnt(0) -> every thread's sc1 H-stores have reached the MALL
//    before thread0 issues its leaf atomic.
//  - reading a fetch_add result forces vmcnt(0) (in-order retirement) -> the leaf/root reset
//    stores are globally visible before the next-level atomic / gen flip is issued.
__device__ __forceinline__ void grid_barrier(int* bar) {
    __syncthreads();
    if (threadIdx.x == 0) {
        const int grp = blockIdx.x & 7;
        int gen = __hip_atomic_load(bar + 288, __ATOMIC_RELAXED, __HIP_MEMORY_SCOPE_AGENT);
        if (__hip_atomic_fetch_add(bar + grp * 32, 1, __ATOMIC_RELAXED, __HIP_MEMORY_SCOPE_AGENT)
            == (NWG / 8 - 1)) {
            __hip_atomic_store(bar + grp * 32, 0, __ATOMIC_RELAXED, __HIP_MEMORY_SCOPE_AGENT);
            if (__hip_atomic_fetch_add(bar + 256, 1, __ATOMIC_RELAXED, __HIP_MEMORY_SCOPE_AGENT) == 7) {
                __hip_atomic_store(bar + 256, 0, __ATOMIC_RELAXED, __HIP_MEMORY_SCOPE_AGENT);
                __hip_atomic_store(bar + 288, gen + 1, __ATOMIC_RELAXED, __HIP_MEMORY_SCOPE_AGENT);
            }
        }
        while (__hip_atomic_load(bar + 288, __ATOMIC_RELAXED, __HIP_MEMORY_SCOPE_AGENT) == gen) {
            __builtin_amdgcn_s_sleep(2);
        }
    }
    __syncthreads();
}

// ---------------- barrier diagnostic: 256 pure grid barriers, nothing else ----------------
__global__ void __launch_bounds__(256, 1) bar_diag_kernel(int* bar) {
    for (int p = 0; p < 256; ++p) grid_barrier(bar);
}

// ---------------- sequential persistent kernel ----------------
// WGs 0..63: layer0, 16 units each. WGs 64..191: layer1 (one step behind), 8 units each.
// H0/H1 slot s = step (s-2) output; slot0 = zeros, slot1 = initial h.
// H reads: plain cached loads (write-once slots). H writes: sc0/sc1 write-through.
// 64 KiB static LDS pins: L0 -> ig/fg gate rows of Whh0 (32 rows x 2KB); L1 -> all Wih1 rows
// (32 rows x 2KB). XOR swizzle: frag f of row rL stored at byte rL*2048 + ((f*16)^((rL&7)<<4)).
__global__ void __launch_bounds__(256, 1) seq_kernel(
    unsigned short* __restrict__ H0, unsigned short* __restrict__ H1,
    const unsigned short* __restrict__ Xp,
    const unsigned short* __restrict__ Whh0, const unsigned short* __restrict__ Wih1,
    const unsigned short* __restrict__ Whh1,
    const unsigned short* __restrict__ Wh2T0, const unsigned short* __restrict__ Wh2T1,
    const float* __restrict__ bias1, int* bar,
    const float* __restrict__ c0_in, const int* __restrict__ mask,
    const float* __restrict__ bh2_0, const float* __restrict__ bh2_1)
{
    __shared__ unsigned short ldsw[32768];   // 64 KiB
    const int wg = blockIdx.x;
    const int lane = threadIdx.x & 63;
    const int wave = threadIdx.x >> 6;
    const int q = lane >> 4, c = lane & 15;
    const int m0 = wave * 16;
    const size_t BH = (size_t)BATCH * HID;

    // ---- stage weights into LDS (once) ----
    {
        const int jb = (wg < NWG_L0) ? wg * 16 : (wg - NWG_L0) * 8;
        for (int i = threadIdx.x; i < 4096; i += 256) {
            const int rL = i >> 7, f = i & 127;
            const unsigned short* src;
            if (wg < NWG_L0) {
                // rows 0..15: ig units 0..15; rows 16..31: fg units 0..15
                src = Whh0 + ((size_t)((rL >> 4) * 1024 + jb + (rL & 15))) * HID + f * 8;
            } else {
                // rows g*8+u, g=0..3 (ig,fg,gg,og), u=0..7, from Wih1
                src = Wih1 + ((size_t)((rL >> 3) * 1024 + jb + (rL & 7))) * HID + f * 8;
            }
            *(bf16x8*)((char*)ldsw + rL * 2048 + ((f * 16) ^ ((rL & 7) << 4))) = *(const bf16x8*)src;
        }
        __syncthreads();
    }
    const char* lw = (const char*)ldsw;
    const unsigned xorv = (unsigned)(c & 7) << 4;

    if (wg < NWG_L0) {
        // ---- layer 0, units j0..j0+15; ig/fg weights from LDS, gg/og + skip from global(L2)
        const int j0 = wg * 16;
        const int j = j0 + c;
        f32x4 creg;
#pragma unroll
        for (int r = 0; r < 4; ++r) creg[r] = c0_in[(size_t)(m0 + q * 4 + r) * HID + j];
        const unsigned lb0 = (unsigned)c * 2048;          // ig row (LDS)
        const unsigned lb1 = (unsigned)(16 + c) * 2048;   // fg row (LDS)
        const unsigned short* b2p = Whh0 + (size_t)(j + 2048) * HID + 8 * q;   // gg
        const unsigned short* b3p = Whh0 + (size_t)(j + 3072) * HID + 8 * q;   // og
        const unsigned short* bsp = Wh2T0 + (size_t)j * HID + 8 * q;
        const float bsk = bh2_0[j];

        for (int p = 0; p <= TSEQ; ++p) {
            if (p < TSEQ) {
                const unsigned short* arow = H0 + (size_t)(p + 1) * BH + (size_t)(m0 + c) * HID + 8 * q;
                const unsigned short* srow = H0 + (size_t)p * BH + (size_t)(m0 + c) * HID + 8 * q;
                // early independent loads: mask code + Xp gate biases (nt: read-once stream)
                const int code = mask[(size_t)p * 2048 + j];
                const unsigned short* xpt = Xp + (size_t)p * BATCH * G4;
                unsigned short xraw[16];
#pragma unroll
                for (int r = 0; r < 4; ++r) {
                    const unsigned short* xr = xpt + (size_t)(m0 + q * 4 + r) * G4 + j;
                    xraw[r * 4 + 0] = __builtin_nontemporal_load(xr);
                    xraw[r * 4 + 1] = __builtin_nontemporal_load(xr + 1024);
                    xraw[r * 4 + 2] = __builtin_nontemporal_load(xr + 2048);
                    xraw[r * 4 + 3] = __builtin_nontemporal_load(xr + 3072);
                }
                f32x4 a0 = {}, a1 = {}, a2 = {}, a3 = {}, as = {};
#pragma unroll
                for (int it = 0; it < 32; ++it) {
                    const unsigned ko = ((unsigned)(it * 64) + (unsigned)(q * 16)) ^ xorv;
                    bf16x8 b0 = *(const bf16x8*)(lw + lb0 + ko);
                    bf16x8 b1 = *(const bf16x8*)(lw + lb1 + ko);
                    const int k = it * 32;
                    bf16x8 af = *(const bf16x8*)(arow + k);
                    bf16x8 b2 = *(const bf16x8*)(b2p + k);
                    bf16x8 b3 = *(const bf16x8*)(b3p + k);
                    bf16x8 sf = *(const bf16x8*)(srow + k);
                    bf16x8 bs = *(const bf16x8*)(bsp + k);
                    a0 = MFMA16(af, b0, a0);
                    a1 = MFMA16(af, b1, a1);
                    a2 = MFMA16(af, b2, a2);
                    a3 = MFMA16(af, b3, a3);
                    as = MFMA16(sf, bs, as);
                }
                const float m1 = (code == 0 || code == 2) ? 1.f : 0.f;
                const float m2 = (code == 1 || code == 2) ? 1.f : 0.f;
                unsigned short* hout = H0 + (size_t)(p + 2) * BH;
#pragma unroll
                for (int r = 0; r < 4; ++r) {
                    const int m = m0 + q * 4 + r;
                    float ig = a0[r] + bf2f(xraw[r * 4 + 0]);
                    float fg = a1[r] + bf2f(xraw[r * 4 + 1]);
                    float gg = a2[r] + bf2f(xraw[r * 4 + 2]);
                    float og = a3[r] + bf2f(xraw[r * 4 + 3]);
                    float cn = sigm(fg) * creg[r] + sigm(ig) * tanh_f(gg);
                    float h1v = sigm(og) * tanh_f(cn);
                    float h2v = sigm(as[r] + bsk);
                    creg[r] = cn;
                    stvol(hout + (size_t)m * HID + j, f2bf(h1v * m1 + h2v * m2));
                }
            }
            grid_barrier(bar);
        }
    } else {
        // ---- layer 1 (step p-1), units j0..j0+7. Wih1 from LDS; Whh1 + skip from global(L2).
        const int w1 = wg - NWG_L0;
        const int j0 = w1 * 8;
        const int cj = c & 7, chi = c >> 3;
        const int j = j0 + cj;
        f32x4 creg;
#pragma unroll
        for (int r = 0; r < 4; ++r) creg[r] = c0_in[BH + (size_t)(m0 + q * 4 + r) * HID + j];
        const size_t rowA = (size_t)(j + 1024 * chi) * HID;        // ig (chi=0) | fg (chi=1)
        const size_t rowB = (size_t)(j + 1024 * (2 + chi)) * HID;  // gg | og
        const unsigned lbA = (unsigned)(chi * 8 + cj) * 2048;        // Wih1 gate chi (LDS)
        const unsigned lbB = (unsigned)((2 + chi) * 8 + cj) * 2048;  // Wih1 gate 2+chi (LDS)
        const unsigned short* bh0 = Whh1 + rowA + 8 * q;
        const unsigned short* bh1 = Whh1 + rowB + 8 * q;
        const unsigned short* bsp = Wh2T1 + (size_t)j * HID + 8 * q;
        const float bsk = bh2_1[j];
        const float bg0 = bias1[j], bg1 = bias1[j + 1024], bg2 = bias1[j + 2048], bg3 = bias1[j + 3072];

        for (int p = 0; p <= TSEQ; ++p) {
            if (p >= 1) {
                const int t = p - 1;
                const unsigned short* aih = H0 + (size_t)(p + 1) * BH + (size_t)(m0 + c) * HID + 8 * q;
                const unsigned short* ahh = H1 + (size_t)p * BH + (size_t)(m0 + c) * HID + 8 * q;
                const unsigned short* ask = H1 + (size_t)(p - 1) * BH + (size_t)(m0 + c) * HID + 8 * q;
                const int code = mask[(size_t)t * 2048 + 1024 + j];
                f32x4 x0 = {}, x1 = {}, y0 = {}, y1 = {}, as = {};
#pragma unroll
                for (int it = 0; it < 32; ++it) {
                    const unsigned ko = ((unsigned)(it * 64) + (unsigned)(q * 16)) ^ xorv;
                    bf16x8 w0 = *(const bf16x8*)(lw + lbA + ko);
                    bf16x8 w1v = *(const bf16x8*)(lw + lbB + ko);
                    const int k = it * 32;
                    bf16x8 fi = *(const bf16x8*)(aih + k);
                    x0 = MFMA16(fi, w0, x0);
                    x1 = MFMA16(fi, w1v, x1);
                    bf16x8 fh = *(const bf16x8*)(ahh + k);
                    bf16x8 u0 = *(const bf16x8*)(bh0 + k);
                    bf16x8 u1 = *(const bf16x8*)(bh1 + k);
                    y0 = MFMA16(fh, u0, y0);
                    y1 = MFMA16(fh, u1, y1);
                    bf16x8 fs = *(const bf16x8*)(ask + k);
                    bf16x8 ws_ = *(const bf16x8*)(bsp + k);
                    as = MFMA16(fs, ws_, as);
                }
                const float m1 = (code == 0 || code == 2) ? 1.f : 0.f;
                const float m2 = (code == 1 || code == 2) ? 1.f : 0.f;
                unsigned short* hout = H1 + (size_t)(p + 1) * BH;
#pragma unroll
                for (int r = 0; r < 4; ++r) {
                    float t0 = x0[r] + y0[r];               // chi=0: ig[j], chi=1: fg[j]
                    float t1 = x1[r] + y1[r];               // chi=0: gg[j], chi=1: og[j]
                    float pt0 = __shfl_xor(t0, 8, 64);
                    float pt1 = __shfl_xor(t1, 8, 64);
                    if (chi == 0) {
                        float ig = t0 + bg0, fg = pt0 + bg1, gg = t1 + bg2, og = pt1 + bg3;
                        float cn = sigm(fg) * creg[r] + sigm(ig) * tanh_f(gg);
                        float h1v = sigm(og) * tanh_f(cn);
                        float h2v = sigm(as[r] + bsk);
                        creg[r] = cn;
                        const int m = m0 + q * 4 + r;
                        stvol(hout + (size_t)m * HID + j, f2bf(h1v * m1 + h2v * m2));
                    }
                }
            }
            grid_barrier(bar);
        }
    }
}

// ---------------- host ----------------
extern "C" void kernel_launch(void* const* d_in, const int* in_sizes, int n_in,
                              void* d_out, int out_size, void* d_ws, size_t ws_size,
                              hipStream_t stream) {
    const float* targets = (const float*)d_in[0];
    const float* h0_in   = (const float*)d_in[1];
    const float* c0_in   = (const float*)d_in[2];
    const int*   mask    = (const int*)d_in[3];
    const float* W_ih0 = (const float*)d_in[4];
    const float* W_hh0 = (const float*)d_in[5];
    const float* b_ih0 = (const float*)d_in[6];
    const float* b_hh0 = (const float*)d_in[7];
    const float* W_ih1 = (const float*)d_in[8];
    const float* W_hh1 = (const float*)d_in[9];
    const float* b_ih1 = (const float*)d_in[10];
    const float* b_hh1 = (const float*)d_in[11];
    const float* Wh2_0 = (const float*)d_in[12];
    const float* bh2_0 = (const float*)d_in[13];
    const float* Wh2_1 = (const float*)d_in[14];
    const float* bh2_1 = (const float*)d_in[15];
    const float* W_out = (const float*)d_in[16];
    const float* b_out = (const float*)d_in[17];

    char* ws = (char*)d_ws;
    size_t off = 0;
    auto take = [&](size_t bytes) { size_t o = off; off += (bytes + 255) & ~(size_t)255; return o; };
    unsigned short* Xp    = (unsigned short*)(ws + take((size_t)TSEQ * BATCH * G4 * 2));
    unsigned short* H0    = (unsigned short*)(ws + take((size_t)(TSEQ + 2) * BATCH * HID * 2));
    unsigned short* H1    = (unsigned short*)(ws + take((size_t)(TSEQ + 2) * BATCH * HID * 2));
    unsigned short* Wih0b = (unsigned short*)(ws + take((size_t)G4 * IN0 * 2));
    unsigned short* Whh0b = (unsigned short*)(ws + take((size_t)G4 * HID * 2));
    unsigned short* Wih1b = (unsigned short*)(ws + take((size_t)G4 * HID * 2));
    unsigned short* Whh1b = (unsigned short*)(ws + take((size_t)G4 * HID * 2));
    unsigned short* Wh2T0b = (unsigned short*)(ws + take((size_t)HID * HID * 2));
    unsigned short* Wh2T1b = (unsigned short*)(ws + take((size_t)HID * HID * 2));
    unsigned short* Woutb  = (unsigned short*)(ws + take((size_t)NOUT * HID * 2));
    float* bias1 = (float*)(ws + take(4096 * 4));
    int*   bar   = (int*)(ws + take(4096));

    prep_kernel<<<2048, 256, 0, stream>>>(W_ih0, W_hh0, W_ih1, W_hh1, Wh2_0, Wh2_1, W_out,
                                          b_ih1, b_hh1, h0_in,
                                          Wih0b, Whh0b, Wih1b, Whh1b, Wh2T0b, Wh2T1b, Woutb,
                                          bias1, H0, H1, bar);

    xproj_kernel<<<dim3(G4 / 64, TSEQ * BATCH / 64), 256, 0, stream>>>(targets, Wih0b, Xp, b_ih0, b_hh0);

    // PLAIN launch: barrier is hand-rolled (no coop-groups API); 192 blocks @ launch_bounds(256,1)
    // on an idle 256-CU device are all co-resident.
    seq_kernel<<<dim3(NWG), dim3(256), 0, stream>>>(H0, H1, Xp, Whh0b, Wih1b, Whh1b,
                                                    Wh2T0b, Wh2T1b, bias1, bar,
                                                    c0_in, mask, bh2_0, bh2_1);

    outproj_kernel<<<dim3(NOUT / 64, TSEQ * BATCH / 64), 256, 0, stream>>>(
        H1 + 2 * (size_t)BATCH * HID, Woutb, (float*)d_out, b_out);

    // diagnostic: 256 pure grid barriers on a separate counter region (bar + 512 ints)
    bar_diag_kernel<<<dim3(NWG), dim3(256), 0, stream>>>(bar + 512);
}

// Round 5
// 17616.110 us; speedup vs baseline: 1.5580x; 1.0176x over previous
//
#include <hip/hip_runtime.h>
#include <hip/hip_bf16.h>

// Decoder_4217657885137: 2-layer LSTM + per-unit random skip-mix, T=512, B=64, H=1024.
//   1) prep_kernel: fp32->bf16 weight conversion (+Wh2 transpose), bias fusion, h-history init, barrier zeroing
//   2) xproj_kernel: Xp[t,b,:] = targets @ W_ih0^T + b_ih0 + b_hh0   (batched over all T; bf16 MFMA)
//   3) seq_kernel (persistent, 192 WGs, PLAIN launch):
//      513 phases; phase p computes layer0(step p) and layer1(step p-1); one grid barrier per phase.
//      R2: relaxed MALL-homed barrier. R3: atomic loads+prefetch (null). R4: plain cached H loads
//      (null). R5: 64KiB LDS weight pinning + nt Xp -> FETCH 6.2GB->1.07GB, seq 21.8->12.85ms;
//      bar_diag isolated the barrier at ~2us/phase (~1ms total) -> barrier NOT the floor.
//      R6 THEORY: phase=25us vs ~6us of modeled work; VGPR=92 says the compiler holds only ~3
//        loads in flight -> k-loop = serialized L2/MALL latency windows. Occupancy is pinned at
//        1 wave/SIMD (192 WGs, 256 CUs), so ~512 VGPR/wave budget is unused.
//      R6 CHANGES:
//        a) rolling register prefetch with PLAIN CACHED loads over ALL global streams
//           (L0: 5 streams x depth 6; L1: 6 streams x depth 5; ~30 loads in flight/wave,
//           fully unrolled static indices -> registers, no scratch).
//        b) bar_diag removed (question answered; it cost 0.5ms of score).
//   4) outproj_kernel: y = H1 @ W_out^T + b_out (batched)

#define HID   1024
#define BATCH 64
#define TSEQ  512
#define G4    4096
#define IN0   1536
#define NOUT  512
#define NWG   192
#define NWG_L0 64

typedef __attribute__((ext_vector_type(8))) short bf16x8;
typedef __attribute__((ext_vector_type(4))) float f32x4;

#define MFMA16(a,b,c) __builtin_amdgcn_mfma_f32_16x16x32_bf16((a),(b),(c),0,0,0)

__device__ __forceinline__ float bf2f(unsigned short u) {
    return __uint_as_float(((unsigned)u) << 16);
}
__device__ __forceinline__ unsigned short f2bf(float f) {
    unsigned u = __float_as_uint(f);
    u += 0x7fffu + ((u >> 16) & 1u);   // RNE
    return (unsigned short)(u >> 16);
}
__device__ __forceinline__ float sigm(float x)   { return 1.0f / (1.0f + __expf(-x)); }
__device__ __forceinline__ float tanh_f(float x) { return 1.0f - 2.0f / (1.0f + __expf(2.0f * x)); }

// Coherent H store: volatile 2B -> global_store_short sc0 sc1 (write-through to MALL, the
// cross-XCD coherence point; single instruction, no tearing).
__device__ __forceinline__ void stvol(unsigned short* p, unsigned short v) {
    *(volatile unsigned short*)p = v;
}

// ---------------- prep ----------------
__global__ void prep_kernel(const float* W_ih0, const float* W_hh0, const float* W_ih1, const float* W_hh1,
                            const float* Wh2_0, const float* Wh2_1, const float* W_out,
                            const float* b_ih1, const float* b_hh1, const float* h0_in,
                            unsigned short* Wih0b, unsigned short* Whh0b, unsigned short* Wih1b,
                            unsigned short* Whh1b, unsigned short* Wh2T0b, unsigned short* Wh2T1b,
                            unsigned short* Woutb, float* bias1, unsigned short* H0, unsigned short* H1, int* bar)
{
    const size_t NW0 = (size_t)G4 * IN0;      // 6291456
    const size_t NW  = (size_t)G4 * HID;      // 4194304
    const size_t NT  = (size_t)HID * HID;     // 1048576
    const size_t NO  = (size_t)NOUT * HID;    // 524288
    const size_t NB  = 4096;
    const size_t NH2 = 2 * (size_t)BATCH * HID; // slot0 zeros + slot1 init
    const size_t total = NW0 + 3 * NW + 2 * NT + NO + NB + 2 * NH2 + 1024;
    for (size_t i = (size_t)blockIdx.x * blockDim.x + threadIdx.x; i < total;
         i += (size_t)gridDim.x * blockDim.x) {
        size_t x = i;
        if (x < NW0) { Wih0b[x] = f2bf(W_ih0[x]); continue; } x -= NW0;
        if (x < NW)  { Whh0b[x] = f2bf(W_hh0[x]); continue; } x -= NW;
        if (x < NW)  { Wih1b[x] = f2bf(W_ih1[x]); continue; } x -= NW;
        if (x < NW)  { Whh1b[x] = f2bf(W_hh1[x]); continue; } x -= NW;
        if (x < NT)  { size_t j = x >> 10, k = x & 1023; Wh2T0b[x] = f2bf(Wh2_0[k * HID + j]); continue; } x -= NT;
        if (x < NT)  { size_t j = x >> 10, k = x & 1023; Wh2T1b[x] = f2bf(Wh2_1[k * HID + j]); continue; } x -= NT;
        if (x < NO)  { Woutb[x] = f2bf(W_out[x]); continue; } x -= NO;
        if (x < NB)  { bias1[x] = b_ih1[x] + b_hh1[x]; continue; } x -= NB;
        if (x < NH2) { H0[x] = (x < (size_t)BATCH * HID) ? (unsigned short)0
                                                         : f2bf(h0_in[x - (size_t)BATCH * HID]); continue; } x -= NH2;
        if (x < NH2) { H1[x] = (x < (size_t)BATCH * HID) ? (unsigned short)0
                                                         : f2bf(h0_in[(size_t)BATCH * HID + (x - (size_t)BATCH * HID)]); continue; } x -= NH2;
        bar[x] = 0;
    }
}

// ---------------- xproj: Xp = targets @ W_ih0^T + b_ih0 + b_hh0 ----------------
__global__ void __launch_bounds__(256) xproj_kernel(const float* __restrict__ A,
        const unsigned short* __restrict__ Bw, unsigned short* __restrict__ C,
        const float* __restrict__ bi, const float* __restrict__ bh)
{
    const int lane = threadIdx.x & 63, wave = threadIdx.x >> 6;
    const int q = lane >> 4, c = lane & 15;
    const int m0 = blockIdx.y * 64 + wave * 16;
    const int n0 = blockIdx.x * 64;
    const float* arow = A + (size_t)(m0 + c) * IN0 + 8 * q;
    const unsigned short* b0p = Bw + (size_t)(n0 + c) * IN0 + 8 * q;
    const unsigned short* b1p = b0p + (size_t)16 * IN0;
    const unsigned short* b2p = b0p + (size_t)32 * IN0;
    const unsigned short* b3p = b0p + (size_t)48 * IN0;
    f32x4 a0 = {}, a1 = {}, a2 = {}, a3 = {};
    for (int k = 0; k < IN0; k += 32) {
        float4 f0 = *(const float4*)(arow + k);
        float4 f1 = *(const float4*)(arow + k + 4);
        bf16x8 af;
        af[0] = (short)f2bf(f0.x); af[1] = (short)f2bf(f0.y);
        af[2] = (short)f2bf(f0.z); af[3] = (short)f2bf(f0.w);
        af[4] = (short)f2bf(f1.x); af[5] = (short)f2bf(f1.y);
        af[6] = (short)f2bf(f1.z); af[7] = (short)f2bf(f1.w);
        bf16x8 b0 = *(const bf16x8*)(b0p + k);
        bf16x8 b1 = *(const bf16x8*)(b1p + k);
        bf16x8 b2 = *(const bf16x8*)(b2p + k);
        bf16x8 b3 = *(const bf16x8*)(b3p + k);
        a0 = MFMA16(af, b0, a0);
        a1 = MFMA16(af, b1, a1);
        a2 = MFMA16(af, b2, a2);
        a3 = MFMA16(af, b3, a3);
    }
#pragma unroll
    for (int r = 0; r < 4; ++r) {
        const int m = m0 + q * 4 + r;
        unsigned short* crow = C + (size_t)m * G4 + n0 + c;
        crow[0]  = f2bf(a0[r] + bi[n0 + c]      + bh[n0 + c]);
        crow[16] = f2bf(a1[r] + bi[n0 + 16 + c] + bh[n0 + 16 + c]);
        crow[32] = f2bf(a2[r] + bi[n0 + 32 + c] + bh[n0 + 32 + c]);
        crow[48] = f2bf(a3[r] + bi[n0 + 48 + c] + bh[n0 + 48 + c]);
    }
}

// ---------------- outproj: y = H1 @ W_out^T + b_out ----------------
__global__ void __launch_bounds__(256) outproj_kernel(const unsigned short* __restrict__ A,
        const unsigned short* __restrict__ Bw, float* __restrict__ C, const float* __restrict__ bo)
{
    const int lane = threadIdx.x & 63, wave = threadIdx.x >> 6;
    const int q = lane >> 4, c = lane & 15;
    const int m0 = blockIdx.y * 64 + wave * 16;
    const int n0 = blockIdx.x * 64;
    const unsigned short* arow = A + (size_t)(m0 + c) * HID + 8 * q;
    const unsigned short* b0p = Bw + (size_t)(n0 + c) * HID + 8 * q;
    const unsigned short* b1p = b0p + (size_t)16 * HID;
    const unsigned short* b2p = b0p + (size_t)32 * HID;
    const unsigned short* b3p = b0p + (size_t)48 * HID;
    f32x4 a0 = {}, a1 = {}, a2 = {}, a3 = {};
    for (int k = 0; k < HID; k += 32) {
        bf16x8 af = *(const bf16x8*)(arow + k);
        bf16x8 b0 = *(const bf16x8*)(b0p + k);
        bf16x8 b1 = *(const bf16x8*)(b1p + k);
        bf16x8 b2 = *(const bf16x8*)(b2p + k);
        bf16x8 b3 = *(const bf16x8*)(b3p + k);
        a0 = MFMA16(af, b0, a0);
        a1 = MFMA16(af, b1, a1);
        a2 = MFMA16(af, b2, a2);
        a3 = MFMA16(af, b3, a3);
    }
#pragma unroll
    for (int r = 0; r < 4; ++r) {
        const int m = m0 + q * 4 + r;
        float* crow = C + (size_t)m * NOUT + n0 + c;
        crow[0]  = a0[r] + bo[n0 + c];
        crow[16] = a1[r] + bo[n0 + 16 + c];
        crow[32] = a2[r] + bo[n0 + 32 + c];
        crow[48] = a3[r] + bo[n0 + 48 + c];
    }
}

// ---------------- grid barrier (two-level, all-RELAXED agent atomics, NO cache maintenance) ------
// Leaf counters bar[grp*32] (grp=0..7, one 128B line each, 24 WGs per leaf), root bar[256],
// generation bar[288]. H stores are sc0/sc1 write-through (MALL-homed):
//  - __syncthreads() drains vmcnt(0) -> every thread's sc1 H-stores have reached the MALL
//    before thread0 issues its leaf atomic.
//  - reading a fetch_add result forces vmcnt(0) (in-order retirement) -> the leaf/root reset
//    stores are globally visible before the next-level atomic / gen flip is issued.
__device__ __forceinline__ void grid_barrier(int* bar) {
    __syncthreads();
    if (threadIdx.x == 0) {
        const int grp = blockIdx.x & 7;
        int gen = __hip_atomic_load(bar + 288, __ATOMIC_RELAXED, __HIP_MEMORY_SCOPE_AGENT);
        if (__hip_atomic_fetch_add(bar + grp * 32, 1, __ATOMIC_RELAXED, __HIP_MEMORY_SCOPE_AGENT)
            == (NWG / 8 - 1)) {
            __hip_atomic_store(bar + grp * 32, 0, __ATOMIC_RELAXED, __HIP_MEMORY_SCOPE_AGENT);
            if (__hip_atomic_fetch_add(bar + 256, 1, __ATOMIC_RELAXED, __HIP_MEMORY_SCOPE_AGENT) == 7) {
                __hip_atomic_store(bar + 256, 0, __ATOMIC_RELAXED, __HIP_MEMORY_SCOPE_AGENT);
                __hip_atomic_store(bar + 288, gen + 1, __ATOMIC_RELAXED, __HIP_MEMORY_SCOPE_AGENT);
            }
        }
        while (__hip_atomic_load(bar + 288, __ATOMIC_RELAXED, __HIP_MEMORY_SCOPE_AGENT) == gen) {
            __builtin_amdgcn_s_sleep(2);
        }
    }
    __syncthreads();
}

// ---------------- sequential persistent kernel ----------------
// WGs 0..63: layer0, 16 units each. WGs 64..191: layer1 (one step behind), 8 units each.
// H0/H1 slot s = step (s-2) output; slot0 = zeros, slot1 = initial h.
// H reads: plain cached loads (write-once slots). H writes: sc0/sc1 write-through.
// 64 KiB static LDS pins: L0 -> ig/fg gate rows of Whh0 (32 rows x 2KB); L1 -> all Wih1 rows
// (32 rows x 2KB). XOR swizzle: frag f of row rL stored at byte rL*2048 + ((f*16)^((rL&7)<<4)).
// All remaining global streams go through a rolling register prefetch (plain cached loads).
__global__ void __launch_bounds__(256, 1) seq_kernel(
    unsigned short* __restrict__ H0, unsigned short* __restrict__ H1,
    const unsigned short* __restrict__ Xp,
    const unsigned short* __restrict__ Whh0, const unsigned short* __restrict__ Wih1,
    const unsigned short* __restrict__ Whh1,
    const unsigned short* __restrict__ Wh2T0, const unsigned short* __restrict__ Wh2T1,
    const float* __restrict__ bias1, int* bar,
    const float* __restrict__ c0_in, const int* __restrict__ mask,
    const float* __restrict__ bh2_0, const float* __restrict__ bh2_1)
{
    __shared__ unsigned short ldsw[32768];   // 64 KiB
    const int wg = blockIdx.x;
    const int lane = threadIdx.x & 63;
    const int wave = threadIdx.x >> 6;
    const int q = lane >> 4, c = lane & 15;
    const int m0 = wave * 16;
    const size_t BH = (size_t)BATCH * HID;

    // ---- stage weights into LDS (once) ----
    {
        const int jb = (wg < NWG_L0) ? wg * 16 : (wg - NWG_L0) * 8;
        for (int i = threadIdx.x; i < 4096; i += 256) {
            const int rL = i >> 7, f = i & 127;
            const unsigned short* src;
            if (wg < NWG_L0) {
                // rows 0..15: ig units 0..15; rows 16..31: fg units 0..15
                src = Whh0 + ((size_t)((rL >> 4) * 1024 + jb + (rL & 15))) * HID + f * 8;
            } else {
                // rows g*8+u, g=0..3 (ig,fg,gg,og), u=0..7, from Wih1
                src = Wih1 + ((size_t)((rL >> 3) * 1024 + jb + (rL & 7))) * HID + f * 8;
            }
            *(bf16x8*)((char*)ldsw + rL * 2048 + ((f * 16) ^ ((rL & 7) << 4))) = *(const bf16x8*)src;
        }
        __syncthreads();
    }
    const char* lw = (const char*)ldsw;
    const unsigned xorv = (unsigned)(c & 7) << 4;

    if (wg < NWG_L0) {
        // ---- layer 0, units j0..j0+15; ig/fg weights from LDS, gg/og + skip from global(L2)
        const int j0 = wg * 16;
        const int j = j0 + c;
        f32x4 creg;
#pragma unroll
        for (int r = 0; r < 4; ++r) creg[r] = c0_in[(size_t)(m0 + q * 4 + r) * HID + j];
        const unsigned lb0 = (unsigned)c * 2048;          // ig row (LDS)
        const unsigned lb1 = (unsigned)(16 + c) * 2048;   // fg row (LDS)
        const unsigned short* b2p = Whh0 + (size_t)(j + 2048) * HID + 8 * q;   // gg
        const unsigned short* b3p = Whh0 + (size_t)(j + 3072) * HID + 8 * q;   // og
        const unsigned short* bsp = Wh2T0 + (size_t)j * HID + 8 * q;
        const float bsk = bh2_0[j];

        for (int p = 0; p <= TSEQ; ++p) {
            if (p < TSEQ) {
                const unsigned short* arow = H0 + (size_t)(p + 1) * BH + (size_t)(m0 + c) * HID + 8 * q;
                const unsigned short* srow = H0 + (size_t)p * BH + (size_t)(m0 + c) * HID + 8 * q;
                // early independent loads: mask code + Xp gate biases (nt: read-once stream)
                const int code = mask[(size_t)p * 2048 + j];
                const unsigned short* xpt = Xp + (size_t)p * BATCH * G4;
                unsigned short xraw[16];
#pragma unroll
                for (int r = 0; r < 4; ++r) {
                    const unsigned short* xr = xpt + (size_t)(m0 + q * 4 + r) * G4 + j;
                    xraw[r * 4 + 0] = __builtin_nontemporal_load(xr);
                    xraw[r * 4 + 1] = __builtin_nontemporal_load(xr + 1024);
                    xraw[r * 4 + 2] = __builtin_nontemporal_load(xr + 2048);
                    xraw[r * 4 + 3] = __builtin_nontemporal_load(xr + 3072);
                }
                // rolling register prefetch: 5 streams x depth 6 (~30 loads in flight, 240 VGPR)
                bf16x8 pa[6], ps[6], p2[6], p3[6], pb[6];
#pragma unroll
                for (int kk = 0; kk < 6; ++kk) {
                    pa[kk] = *(const bf16x8*)(arow + kk * 32);
                    ps[kk] = *(const bf16x8*)(srow + kk * 32);
                    p2[kk] = *(const bf16x8*)(b2p + kk * 32);
                    p3[kk] = *(const bf16x8*)(b3p + kk * 32);
                    pb[kk] = *(const bf16x8*)(bsp + kk * 32);
                }
                f32x4 a0 = {}, a1 = {}, a2 = {}, a3 = {}, as = {};
#pragma unroll
                for (int it = 0; it < 32; ++it) {
                    const int s = it % 6;
                    bf16x8 af = pa[s], sf = ps[s], b2 = p2[s], b3 = p3[s], bs = pb[s];
                    if (it + 6 < 32) {
                        pa[s] = *(const bf16x8*)(arow + (it + 6) * 32);
                        ps[s] = *(const bf16x8*)(srow + (it + 6) * 32);
                        p2[s] = *(const bf16x8*)(b2p + (it + 6) * 32);
                        p3[s] = *(const bf16x8*)(b3p + (it + 6) * 32);
                        pb[s] = *(const bf16x8*)(bsp + (it + 6) * 32);
                    }
                    const unsigned ko = ((unsigned)(it * 64) + (unsigned)(q * 16)) ^ xorv;
                    bf16x8 b0 = *(const bf16x8*)(lw + lb0 + ko);
                    bf16x8 b1 = *(const bf16x8*)(lw + lb1 + ko);
                    a0 = MFMA16(af, b0, a0);
                    a1 = MFMA16(af, b1, a1);
                    a2 = MFMA16(af, b2, a2);
                    a3 = MFMA16(af, b3, a3);
                    as = MFMA16(sf, bs, as);
                }
                const float m1 = (code == 0 || code == 2) ? 1.f : 0.f;
                const float m2 = (code == 1 || code == 2) ? 1.f : 0.f;
                unsigned short* hout = H0 + (size_t)(p + 2) * BH;
#pragma unroll
                for (int r = 0; r < 4; ++r) {
                    const int m = m0 + q * 4 + r;
                    float ig = a0[r] + bf2f(xraw[r * 4 + 0]);
                    float fg = a1[r] + bf2f(xraw[r * 4 + 1]);
                    float gg = a2[r] + bf2f(xraw[r * 4 + 2]);
                    float og = a3[r] + bf2f(xraw[r * 4 + 3]);
                    float cn = sigm(fg) * creg[r] + sigm(ig) * tanh_f(gg);
                    float h1v = sigm(og) * tanh_f(cn);
                    float h2v = sigm(as[r] + bsk);
                    creg[r] = cn;
                    stvol(hout + (size_t)m * HID + j, f2bf(h1v * m1 + h2v * m2));
                }
            }
            grid_barrier(bar);
        }
    } else {
        // ---- layer 1 (step p-1), units j0..j0+7. Wih1 from LDS; Whh1 + skip from global(L2).
        const int w1 = wg - NWG_L0;
        const int j0 = w1 * 8;
        const int cj = c & 7, chi = c >> 3;
        const int j = j0 + cj;
        f32x4 creg;
#pragma unroll
        for (int r = 0; r < 4; ++r) creg[r] = c0_in[BH + (size_t)(m0 + q * 4 + r) * HID + j];
        const size_t rowA = (size_t)(j + 1024 * chi) * HID;        // ig (chi=0) | fg (chi=1)
        const size_t rowB = (size_t)(j + 1024 * (2 + chi)) * HID;  // gg | og
        const unsigned lbA = (unsigned)(chi * 8 + cj) * 2048;        // Wih1 gate chi (LDS)
        const unsigned lbB = (unsigned)((2 + chi) * 8 + cj) * 2048;  // Wih1 gate 2+chi (LDS)
        const unsigned short* bh0 = Whh1 + rowA + 8 * q;
        const unsigned short* bh1 = Whh1 + rowB + 8 * q;
        const unsigned short* bsp = Wh2T1 + (size_t)j * HID + 8 * q;
        const float bsk = bh2_1[j];
        const float bg0 = bias1[j], bg1 = bias1[j + 1024], bg2 = bias1[j + 2048], bg3 = bias1[j + 3072];

        for (int p = 0; p <= TSEQ; ++p) {
            if (p >= 1) {
                const int t = p - 1;
                const unsigned short* aih = H0 + (size_t)(p + 1) * BH + (size_t)(m0 + c) * HID + 8 * q;
                const unsigned short* ahh = H1 + (size_t)p * BH + (size_t)(m0 + c) * HID + 8 * q;
                const unsigned short* ask = H1 + (size_t)(p - 1) * BH + (size_t)(m0 + c) * HID + 8 * q;
                const int code = mask[(size_t)t * 2048 + 1024 + j];
                // rolling register prefetch: 6 streams x depth 5 (~30 loads in flight, 240 VGPR)
                bf16x8 pi[5], ph[5], pk[5], pu0[5], pu1[5], pw[5];
#pragma unroll
                for (int kk = 0; kk < 5; ++kk) {
                    pi[kk]  = *(const bf16x8*)(aih + kk * 32);
                    ph[kk]  = *(const bf16x8*)(ahh + kk * 32);
                    pk[kk]  = *(const bf16x8*)(ask + kk * 32);
                    pu0[kk] = *(const bf16x8*)(bh0 + kk * 32);
                    pu1[kk] = *(const bf16x8*)(bh1 + kk * 32);
                    pw[kk]  = *(const bf16x8*)(bsp + kk * 32);
                }
                f32x4 x0 = {}, x1 = {}, y0 = {}, y1 = {}, as = {};
#pragma unroll
                for (int it = 0; it < 32; ++it) {
                    const int s = it % 5;
                    bf16x8 fi = pi[s], fh = ph[s], fs = pk[s];
                    bf16x8 u0 = pu0[s], u1 = pu1[s], ws_ = pw[s];
                    if (it + 5 < 32) {
                        pi[s]  = *(const bf16x8*)(aih + (it + 5) * 32);
                        ph[s]  = *(const bf16x8*)(ahh + (it + 5) * 32);
                        pk[s]  = *(const bf16x8*)(ask + (it + 5) * 32);
                        pu0[s] = *(const bf16x8*)(bh0 + (it + 5) * 32);
                        pu1[s] = *(const bf16x8*)(bh1 + (it + 5) * 32);
                        pw[s]  = *(const bf16x8*)(bsp + (it + 5) * 32);
                    }
                    const unsigned ko = ((unsigned)(it * 64) + (unsigned)(q * 16)) ^ xorv;
                    bf16x8 w0 = *(const bf16x8*)(lw + lbA + ko);
                    bf16x8 w1v = *(const bf16x8*)(lw + lbB + ko);
                    x0 = MFMA16(fi, w0, x0);
                    x1 = MFMA16(fi, w1v, x1);
                    y0 = MFMA16(fh, u0, y0);
                    y1 = MFMA16(fh, u1, y1);
                    as = MFMA16(fs, ws_, as);
                }
                const float m1 = (code == 0 || code == 2) ? 1.f : 0.f;
                const float m2 = (code == 1 || code == 2) ? 1.f : 0.f;
                unsigned short* hout = H1 + (size_t)(p + 1) * BH;
#pragma unroll
                for (int r = 0; r < 4; ++r) {
                    float t0 = x0[r] + y0[r];               // chi=0: ig[j], chi=1: fg[j]
                    float t1 = x1[r] + y1[r];               // chi=0: gg[j], chi=1: og[j]
                    float pt0 = __shfl_xor(t0, 8, 64);
                    float pt1 = __shfl_xor(t1, 8, 64);
                    if (chi == 0) {
                        float ig = t0 + bg0, fg = pt0 + bg1, gg = t1 + bg2, og = pt1 + bg3;
                        float cn = sigm(fg) * creg[r] + sigm(ig) * tanh_f(gg);
                        float h1v = sigm(og) * tanh_f(cn);
                        float h2v = sigm(as[r] + bsk);
                        creg[r] = cn;
                        const int m = m0 + q * 4 + r;
                        stvol(hout + (size_t)m * HID + j, f2bf(h1v * m1 + h2v * m2));
                    }
                }
            }
            grid_barrier(bar);
        }
    }
}

// ---------------- host ----------------
extern "C" void kernel_launch(void* const* d_in, const int* in_sizes, int n_in,
                              void* d_out, int out_size, void* d_ws, size_t ws_size,
                              hipStream_t stream) {
    const float* targets = (const float*)d_in[0];
    const float* h0_in   = (const float*)d_in[1];
    const float* c0_in   = (const float*)d_in[2];
    const int*   mask    = (const int*)d_in[3];
    const float* W_ih0 = (const float*)d_in[4];
    const float* W_hh0 = (const float*)d_in[5];
    const float* b_ih0 = (const float*)d_in[6];
    const float* b_hh0 = (const float*)d_in[7];
    const float* W_ih1 = (const float*)d_in[8];
    const float* W_hh1 = (const float*)d_in[9];
    const float* b_ih1 = (const float*)d_in[10];
    const float* b_hh1 = (const float*)d_in[11];
    const float* Wh2_0 = (const float*)d_in[12];
    const float* bh2_0 = (const float*)d_in[13];
    const float* Wh2_1 = (const float*)d_in[14];
    const float* bh2_1 = (const float*)d_in[15];
    const float* W_out = (const float*)d_in[16];
    const float* b_out = (const float*)d_in[17];

    char* ws = (char*)d_ws;
    size_t off = 0;
    auto take = [&](size_t bytes) { size_t o = off; off += (bytes + 255) & ~(size_t)255; return o; };
    unsigned short* Xp    = (unsigned short*)(ws + take((size_t)TSEQ * BATCH * G4 * 2));
    unsigned short* H0    = (unsigned short*)(ws + take((size_t)(TSEQ + 2) * BATCH * HID * 2));
    unsigned short* H1    = (unsigned short*)(ws + take((size_t)(TSEQ + 2) * BATCH * HID * 2));
    unsigned short* Wih0b = (unsigned short*)(ws + take((size_t)G4 * IN0 * 2));
    unsigned short* Whh0b = (unsigned short*)(ws + take((size_t)G4 * HID * 2));
    unsigned short* Wih1b = (unsigned short*)(ws + take((size_t)G4 * HID * 2));
    unsigned short* Whh1b = (unsigned short*)(ws + take((size_t)G4 * HID * 2));
    unsigned short* Wh2T0b = (unsigned short*)(ws + take((size_t)HID * HID * 2));
    unsigned short* Wh2T1b = (unsigned short*)(ws + take((size_t)HID * HID * 2));
    unsigned short* Woutb  = (unsigned short*)(ws + take((size_t)NOUT * HID * 2));
    float* bias1 = (float*)(ws + take(4096 * 4));
    int*   bar   = (int*)(ws + take(4096));

    prep_kernel<<<2048, 256, 0, stream>>>(W_ih0, W_hh0, W_ih1, W_hh1, Wh2_0, Wh2_1, W_out,
                                          b_ih1, b_hh1, h0_in,
                                          Wih0b, Whh0b, Wih1b, Whh1b, Wh2T0b, Wh2T1b, Woutb,
                                          bias1, H0, H1, bar);

    xproj_kernel<<<dim3(G4 / 64, TSEQ * BATCH / 64), 256, 0, stream>>>(targets, Wih0b, Xp, b_ih0, b_hh0);

    // PLAIN launch: barrier is hand-rolled (no coop-groups API); 192 blocks @ launch_bounds(256,1)
    // on an idle 256-CU device are all co-resident.
    seq_kernel<<<dim3(NWG), dim3(256), 0, stream>>>(H0, H1, Xp, Whh0b, Wih1b, Whh1b,
                                                    Wh2T0b, Wh2T1b, bias1, bar,
                                                    c0_in, mask, bh2_0, bh2_1);

    outproj_kernel<<<dim3(NOUT / 64, TSEQ * BATCH / 64), 256, 0, stream>>>(
        H1 + 2 * (size_t)BATCH * HID, Woutb, (float*)d_out, b_out);
}